// Round 9
// baseline (852.815 us; speedup 1.0000x reference)
//
#include <hip/hip_runtime.h>
#include <cstdint>
#include <cstddef>

// ---------------------------------------------------------------------------
// RPN pipeline, fp64-accurate (ordering-critical: top-k rank + NMS decisions).
// fp32 inputs; all reductions accumulate in double (fp32*fp32 exact in f64).
// ---------------------------------------------------------------------------

typedef unsigned long long ull;
typedef double d4 __attribute__((ext_vector_type(4)));

#define NANCH 9
#define NPIX  2500      // 50*50
#define CIN   512
#define COUT  512
#define KTOT  4608      // 512*9
#define KSEG  2304      // KTOT/2
#define NBOX  22500     // 2500*9
#define TOPK1 10000
#define TOPK2 2000
#define WORDS 157       // ceil(10000/64)
#define NHEAD 45        // 9 cls + 36 box channels
#define HPAD  48        // padded per-pixel stride for head scratch

// ---------------- one-shot weight transpose to tap-major k' ---------------
// wT[(tap*512+ci)*512 + co] = w[co*4608 + ci*9 + tap].  LDS-tiled so both
// global reads and writes are coalesced.  ~2.4M floats, few us.
__global__ __launch_bounds__(256) void wtrans(const float* __restrict__ w,
                                              float* __restrict__ wT) {
  __shared__ float t[36][65];
  const int ci0 = blockIdx.x * 4;    // 4 ci per block -> 36 (tap,ci) rows
  const int co0 = blockIdx.y * 64;
  const int tid = threadIdx.x;
  // read: thread (co_l, cq) reads 9 taps contiguously for one (co,ci)
  const int co_l = tid >> 2, cq = tid & 3;
  const float* src = w + (size_t)(co0 + co_l) * KTOT + (ci0 + cq) * 9;
#pragma unroll
  for (int r = 0; r < 9; ++r) t[r * 4 + cq][co_l] = src[r];
  __syncthreads();
  // write: thread (co_w, rw0) writes 9 rows, coalesced along co
  const int co_w = tid & 63, rw0 = tid >> 6;
#pragma unroll
  for (int m = 0; m < 9; ++m) {
    int rw = rw0 + 4 * m;            // 0..35
    int tap = rw >> 2, cqq = rw & 3;
    wT[((size_t)tap * 512 + ci0 + cqq) * 512 + co0 + co_w] = t[rw][co_w];
  }
}

// ---------------- conv 3x3 as implicit-im2col GEMM, f64 MFMA ---------------
// R14: wave-count x cheap-staging. Tap-major k' (A-tile = shifted masked
// coalesced copy of feat; B coalesced from wT) + 256-thread blocks, grid
// (80,8,2)=1280 = 5 blocks/CU -> 20 waves/CU. 268-271us, MfmaUtil ~61%
// (f64 MFMA floor is 154us). Unchanged since R14.
__global__ __launch_bounds__(256, 5) void conv_gemm(const float* __restrict__ feat,
                                                    const float* __restrict__ wT,
                                                    double* __restrict__ part) {
  const int p0  = blockIdx.x * 32;
  const int co0 = blockIdx.y * 64;
  const int z   = blockIdx.z;
  const int kseg0 = z * KSEG;
  __shared__ float As[2][32][40];   // [buf][k][p]  f32, stride 40 (==8 mod 32)
  __shared__ float Bs[2][32][72];   // [buf][k][co] f32, stride 72 (==8 mod 32)
  const int tid  = threadIdx.x;      // 0..255
  const int lane = tid & 63;
  const int wave = tid >> 6;         // 0..3
  const int quad = lane >> 4;
  const int l16  = lane & 15;
  const int wp = (wave & 1) * 16;    // wave p offset in tile
  const int wc = (wave >> 1) * 32;   // wave co offset in tile
  // A loader: thread = (pixel plA, k-row kAr in 0..7); covers rows kAr+8*jj
  const int plA = tid & 31, kAr = tid >> 5;
  const int pB = p0 + plA;
  const int py = pB / 50, px = pB - py * 50;
  // B loader: thread = (co lane coB, k-row kBr in 0..3); covers rows kBr+4*s
  const int coB = tid & 63, kBr = tid >> 6;

  // ---- layout probe: learn the C/D register->(m,n) mapping ----
  int pmap[4];
  {
    double av_p = (quad == 0) ? (double)(l16 + 1) : (quad == 1 ? 1.0 : 0.0);
    double bv_p = (quad == 0) ? 1.0 : (quad == 1 ? (double)(1000 * (l16 + 1)) : 0.0);
    d4 dp = (d4){0.0, 0.0, 0.0, 0.0};
    dp = __builtin_amdgcn_mfma_f64_16x16x4f64(av_p, bv_p, dp, 0, 0, 0);
#pragma unroll
    for (int r = 0; r < 4; ++r) {
      int iv = (int)(dp[r] + 0.5);
      int mm = iv % 1000 - 1;   // p-id within the 16 block
      int nn = iv / 1000 - 1;   // co-id within the 16 block
      pmap[r] = (mm & 255) | (nn << 8);
    }
  }

  d4 acc[2];
#pragma unroll
  for (int i = 0; i < 2; ++i) acc[i] = (d4){0.0, 0.0, 0.0, 0.0};

  const int NCH = KSEG / 32;   // 72 chunks

  float fa[4], fb[8];

  // A loads for chunk cc: tap constant within chunk -> shifted masked copy
  auto loadA = [&](int cc) {
    int kk0 = kseg0 + cc * 32;
    int tap = kk0 >> 9;             // 0..8
    int ci0 = kk0 & 511;
    int ky = (tap * 11) >> 5;       // tap/3 for tap<9
    int kx = tap - 3 * ky;
    int yy = py + ky - 1, xx = px + kx - 1;
    bool valid = (pB < NPIX) && (yy >= 0) && (yy < 50) && (xx >= 0) && (xx < 50);
    int off = valid ? ((ci0 + kAr) * NPIX + yy * 50 + xx) : 0;
#pragma unroll
    for (int jj = 0; jj < 4; ++jj) {
      float v = feat[off + jj * 8 * NPIX];   // rows kAr+8*jj (in-bounds always)
      fa[jj] = valid ? v : 0.0f;
    }
  };
  // B loads for chunk cc: coalesced rows of wT
  auto loadB = [&](int cc) {
    const float* src = wT + (size_t)(kseg0 + cc * 32 + kBr) * 512 + co0 + coB;
#pragma unroll
    for (int s = 0; s < 8; ++s) fb[s] = src[s * 4 * 512];  // rows kBr+4*s
  };

  // ---- prologue: stage chunk 0 into buf 0; prefetch chunk 1 into regs ----
  loadA(0);
  loadB(0);
#pragma unroll
  for (int jj = 0; jj < 4; ++jj) As[0][kAr + 8 * jj][plA] = fa[jj];
#pragma unroll
  for (int s = 0; s < 8; ++s) Bs[0][kBr + 4 * s][coB] = fb[s];
  loadA(1);
  loadB(1);
  __syncthreads();

  for (int c = 0; c < NCH; ++c) {
    const int buf = c & 1;
    // stage chunk c+1 into the other buffer (regs loaded last iteration)
    if (c + 1 < NCH) {
#pragma unroll
      for (int jj = 0; jj < 4; ++jj) As[buf ^ 1][kAr + 8 * jj][plA] = fa[jj];
#pragma unroll
      for (int s = 0; s < 8; ++s) Bs[buf ^ 1][kBr + 4 * s][coB] = fb[s];
    }
    // issue global loads for chunk c+2 (retire during the MFMA burst)
    if (c + 2 < NCH) {
      loadA(c + 2);
      loadB(c + 2);
    }
    // MFMA burst from buf: 8 k-steps x 2 tile-MFMAs (1 A read feeds 2)
#pragma unroll
    for (int kk = 0; kk < 32; kk += 4) {
      double av  = (double)As[buf][kk + quad][wp + l16];
      double bv0 = (double)Bs[buf][kk + quad][wc + l16];
      double bv1 = (double)Bs[buf][kk + quad][wc + 16 + l16];
      acc[0] = __builtin_amdgcn_mfma_f64_16x16x4f64(av, bv0, acc[0], 0, 0, 0);
      acc[1] = __builtin_amdgcn_mfma_f64_16x16x4f64(av, bv1, acc[1], 0, 0, 0);
    }
    __syncthreads();  // iter-c writes of buf^1 <-> iter-c+1 reads of buf^1
  }
  // epilogue: probe-decoded scatter
  double* basez = part + (size_t)z * COUT * NPIX;
#pragma unroll
  for (int cj = 0; cj < 2; ++cj) {
#pragma unroll
    for (int r = 0; r < 4; ++r) {
      int mm = pmap[r] & 255, nn = pmap[r] >> 8;
      int p  = p0 + wp + mm;
      int co = co0 + wc + cj * 16 + nn;
      if (p < NPIX) basez[(size_t)co * NPIX + p] = acc[cj][r];
    }
  }
}

// ---------------- heads stage 1: output-parallel 1x1-conv GEMM -------------
// R16: R14 (40,12)-grid version (R15's single-pass rewrite collapsed
// concurrency to 40 CUs, +110us; part re-reads are L3-resident and
// latency-hidden by 1920 waves). Summation order co ascending -> numerics
// unchanged.
__global__ __launch_bounds__(256) void heads_mm(
    const double* __restrict__ part, const float* __restrict__ rpn_b,
    const float* __restrict__ cls_w, const float* __restrict__ box_w,
    double* __restrict__ headsc) {
  const int lane = threadIdx.x & 63;
  const int o = __builtin_amdgcn_readfirstlane(blockIdx.y * 4 + (threadIdx.x >> 6));
  if (o >= NHEAD) return;
  const int p = blockIdx.x * 64 + lane;
  const bool act = p < NPIX;
  const int pp = act ? p : 0;
  const float* wsel = (o < 9) ? (cls_w + (size_t)o * CIN)
                              : (box_w + (size_t)(o - 9) * CIN);
  const double* p0 = part + pp;
  const double* p1 = part + (size_t)COUT * NPIX + pp;
  double acc = 0.0;
#pragma unroll 4
  for (int co = 0; co < CIN; ++co) {
    double v = p0[(size_t)co * NPIX] + p1[(size_t)co * NPIX] + (double)rpn_b[co];
    v = v > 0.0 ? v : 0.0;
    acc += (double)wsel[co] * v;
  }
  if (act) headsc[(size_t)p * HPAD + o] = acc;
}

// ---------------- heads stage 2: bias + anchor decode + clamp --------------
__global__ __launch_bounds__(256) void decode_kernel(
    const double* __restrict__ headsc, const float* __restrict__ cls_b,
    const float* __restrict__ box_b, double* __restrict__ logits,
    double* __restrict__ boxesAll, float* __restrict__ out_cls) {
  int idx = blockIdx.x * blockDim.x + threadIdx.x;
  if (idx >= NBOX) return;
  int p = idx / 9, a = idx - p * 9;
  int y = p / 50, x = p - y * 50;
  double sx = 16.0 * (double)x, sy = 16.0 * (double)y;
  const double scs[3] = {128.0, 256.0, 512.0};
  const double ars[3] = {0.5, 1.0, 2.0};
  double ar = ars[a / 3], sc = scs[a - (a / 3) * 3];
  double hr = sqrt(ar), wr = 1.0 / hr;
  double wv = wr * sc, hv = hr * sc;
  // jnp.round == round-half-even == rint under default rounding mode
  double bx0 = rint(-wv * 0.5), by0 = rint(-hv * 0.5);
  double bx1 = rint(wv * 0.5), by1 = rint(hv * 0.5);
  double a0 = sx + bx0, a1 = sy + by0, a2 = sx + bx1, a3 = sy + by1;
  double wA = a2 - a0, hA = a3 - a1;
  double cx = a0 + 0.5 * wA, cy = a1 + 0.5 * hA;
  const double* hp = headsc + (size_t)p * HPAD;
  double dx = hp[9 + a * 4 + 0] + (double)box_b[a * 4 + 0];
  double dy = hp[9 + a * 4 + 1] + (double)box_b[a * 4 + 1];
  double dw = hp[9 + a * 4 + 2] + (double)box_b[a * 4 + 2];
  double dh = hp[9 + a * 4 + 3] + (double)box_b[a * 4 + 3];
  double pcx = wA * dx + cx, pcy = hA * dy + cy;
  double pw = exp(dw) * wA, ph = exp(dh) * hA;
  double b0 = pcx - 0.5 * pw, b1 = pcy - 0.5 * ph;
  double b2 = pcx + 0.5 * pw, b3 = pcy + 0.5 * ph;
  b0 = fmin(fmax(b0, 0.0), 800.0);
  b1 = fmin(fmax(b1, 0.0), 800.0);
  b2 = fmin(fmax(b2, 0.0), 800.0);
  b3 = fmin(fmax(b3, 0.0), 800.0);
  boxesAll[(size_t)idx * 4 + 0] = b0;
  boxesAll[(size_t)idx * 4 + 1] = b1;
  boxesAll[(size_t)idx * 4 + 2] = b2;
  boxesAll[(size_t)idx * 4 + 3] = b3;
  double L = hp[a] + (double)cls_b[a];
  logits[idx] = L;
  out_cls[idx] = (float)L;
}

// ---------------- exact stable descending rank (== jax.lax.top_k order) ---
__global__ __launch_bounds__(256) void rank_count(const double* __restrict__ logits,
                                                  int* __restrict__ ranks) {
  __shared__ double Ls[2048];
  int i = blockIdx.x * 256 + threadIdx.x;
  int j0 = blockIdx.y * 2048;
  int jn = NBOX - j0;
  if (jn > 2048) jn = 2048;
  for (int t = threadIdx.x; t < jn; t += 256) Ls[t] = logits[j0 + t];
  __syncthreads();
  if (i >= NBOX) return;
  double Li = logits[i];
  int cnt = 0;
  for (int t = 0; t < jn; ++t) {
    double Lj = Ls[t];
    int j = j0 + t;
    cnt += (Lj > Li || (Lj == Li && j < i)) ? 1 : 0;
  }
  atomicAdd(&ranks[i], cnt);
}

__global__ __launch_bounds__(256) void scatter_topk(const double* __restrict__ logits,
                                                    const double* __restrict__ boxesAll,
                                                    const int* __restrict__ ranks,
                                                    double* __restrict__ sLog,
                                                    double* __restrict__ sBox) {
  int i = blockIdx.x * 256 + threadIdx.x;
  if (i >= NBOX) return;
  int r = ranks[i];
  if (r < TOPK1) {
    sLog[r] = logits[i];
    sBox[(size_t)r * 4 + 0] = boxesAll[(size_t)i * 4 + 0];
    sBox[(size_t)r * 4 + 1] = boxesAll[(size_t)i * 4 + 1];
    sBox[(size_t)r * 4 + 2] = boxesAll[(size_t)i * 4 + 2];
    sBox[(size_t)r * 4 + 3] = boxesAll[(size_t)i * 4 + 3];
  }
}

// ---------------- pairwise IoU suppression bitmask (upper triangle) --------
// R16: mask is COLUMN-MAJOR mask[word*TOPK1 + row] -> coalesced writes here,
// coalesced A1 staging + L2-local A2 gathers in nms_scan. Same bits.
__global__ __launch_bounds__(256) void iou_mask(const double* __restrict__ sb,
                                                ull* __restrict__ mask) {
  const int it = blockIdx.x;
  const int wt = blockIdx.y;
  if (wt * 4 + 3 < it) return;  // block only needed for words >= i/64
  __shared__ double ib[64][4];
  __shared__ double jb[256][4];
  const int tid = threadIdx.x;
  {
    int ii = it * 64 + (tid >> 2);
    int d = tid & 3;
    ib[tid >> 2][d] = (ii < TOPK1) ? sb[(size_t)ii * 4 + d] : 0.0;
  }
  for (int t = tid; t < 1024; t += 256) {
    int jj = wt * 256 + (t >> 2);
    jb[t >> 2][t & 3] = (jj < TOPK1) ? sb[(size_t)jj * 4 + (t & 3)] : 0.0;
  }
  __syncthreads();
  const int il = tid & 63, wl = tid >> 6;
  const int i = it * 64 + il;
  const int word = wt * 4 + wl;
  if (i >= TOPK1 || word >= WORDS || word < (i >> 6)) return;
  const double x0 = ib[il][0], y0 = ib[il][1], x1 = ib[il][2], y1 = ib[il][3];
  const double areai = (x1 - x0) * (y1 - y0);
  ull bits = 0;
  const int jbase = word * 64;
  for (int b = 0; b < 64; ++b) {
    int j = jbase + b;
    if (j <= i || j >= TOPK1) continue;
    int jl = wl * 64 + b;
    double u0 = jb[jl][0], u1 = jb[jl][1], u2 = jb[jl][2], u3 = jb[jl][3];
    double xl = fmax(x0, u0), yt = fmax(y0, u1);
    double xr = fmin(x1, u2), yb = fmin(y1, u3);
    double iw = xr - xl, ih = yb - yt;
    iw = iw > 0.0 ? iw : 0.0;
    ih = ih > 0.0 ? ih : 0.0;
    double inter = iw * ih;
    double aj = (u2 - u0) * (u3 - u1);
    double un = areai + aj - inter;
    // reference: inter/un > 0.7 (0/0 -> NaN -> false). Multiply form matches.
    if (inter > 0.7 * un) bits |= 1ull << b;
  }
  mask[(size_t)word * TOPK1 + i] = bits;
}

// ---------------- tiled greedy-NMS scan, software-pipelined ----------------
// R17: overlap fix. R16 counters: 271us, Occupancy 0.05%, VALU 0.02% -- pure
// latency serialization of {A1 staging, A2 gathers, 2 barriers x 157 groups}
// with the wave0-only resolve. Now: while wave0 resolves tile T (forward-
// update done IN-WAVE via shfl_xor OR-reduce -> zero per-group barriers),
// waves 1-3 stage tile T+1 (double-buffered tileRows) and compute its base
// removal-OR over the stable klist prefix [0..kcStart). After one joint
// barrier, wave0 gathers the small delta (kept-during-T rows x T+1 words),
// tid<8 folds 32 partials, tile advances. 3 barriers/tile (60 total) vs
// ~350; all staging latency hidden under the serial resolve. Keep decisions
// BIT-IDENTICAL: same resolve math, removal-OR = base ∪ delta = all
// previously-kept, same early-exit (keepwords memset covers the tail).
#define NTILE 8
#define TRS   9     // padded ull stride for tileRows (8 words + 1 pad)
#define KCAP  2112
#define NT    ((WORDS + NTILE - 1) / NTILE)   // 20 tiles

__global__ __launch_bounds__(256) void nms_scan(const ull* __restrict__ mask,
                                                ull* __restrict__ keepwords) {
  __shared__ ull tileRows[2][512 * TRS];     // 73,728 B (double-buffered)
  __shared__ int klist[KCAP];                // kept global indices (rank order)
  __shared__ ull remvPart[32][NTILE + 1];    // column-OR partials (next tile)
  __shared__ ull remvA[NTILE];               // current-tile removal words
  __shared__ int newk[64];                   // this group's kept local rows
  __shared__ int kcLds, doneLds;
  const int tid = threadIdx.x;
  const int lane = tid & 63;
  const int wave = tid >> 6;

  if (tid == 0) { kcLds = 0; doneLds = 0; }
  if (tid < NTILE) remvA[tid] = 0;           // tile 0 has no prior kept
  __syncthreads();

  // ---- prologue: stage tile 0 into buf 0 (all 256 threads) ----
  for (int idx = tid; idx < NTILE * 512; idx += 256) {
    int w = idx >> 9, row = idx & 511;
    ull v = (row < TOPK1) ? mask[(size_t)w * TOPK1 + row] : 0;  // G0 = 0
    tileRows[0][row * TRS + w] = v;
  }
  __syncthreads();

  int buf = 0;
  for (int T = 0; T < NT; ++T) {
    const int G0 = T * NTILE;
    const int TW = (WORDS - G0 < NTILE) ? (WORDS - G0) : NTILE;
    const int kcStart = kcLds;               // uniform snapshot (post-barrier)
    const int G0n = G0 + NTILE;
    const int TWn = (WORDS - G0n < NTILE) ? (WORDS - G0n) : NTILE;

    if (wave == 0) {
      // ---- Phase B: serial resolve of this tile's TW groups (wave0) ----
      int kc = kcStart;
      int done = 0;
      for (int gi = 0; gi < TW; ++gi) {
        const int g = G0 + gi;
        ull cur = remvA[gi];
        {
          unsigned int clo = __builtin_amdgcn_readfirstlane((unsigned int)cur);
          unsigned int chi = __builtin_amdgcn_readfirstlane((unsigned int)(cur >> 32));
          cur = ((ull)chi << 32) | clo;
        }
        ull mrow = tileRows[buf][(gi * 64 + lane) * TRS + gi];
        const unsigned int ml = (unsigned int)mrow;
        const unsigned int mh = (unsigned int)(mrow >> 32);
        const ull validm = (g == WORDS - 1) ? 0xFFFFull : ~0ull;
        ull rem = (~cur) & validm;
        while (rem) {
          int b = __ffsll((long long)rem) - 1;
          b = __builtin_amdgcn_readfirstlane(b);
          ull m = ((ull)(unsigned int)__builtin_amdgcn_readlane((int)mh, b) << 32) |
                  (unsigned int)__builtin_amdgcn_readlane((int)ml, b);
          cur |= m;
          ull above = (b == 63) ? 0ull : (~0ull << (b + 1));
          rem = (~cur) & rem & above;
        }
        ull kb = (~cur) & validm;
        if (lane == 0) keepwords[g] = kb;
        int nk = __popcll(kb);
        if ((kb >> lane) & 1ull) {
          int ofs = __popcll(lane ? (kb & ((1ull << lane) - 1ull)) : 0ull);
          klist[kc + ofs] = g * 64 + lane;
          newk[ofs] = gi * 64 + lane;
        }
        kc += nk;
        if (kc >= TOPK2) done = 1;
        // in-wave forward update of remaining words (no barrier)
        if (!done && gi + 1 < TW && nk > 0) {
          int w = lane & 7, s = lane >> 3;   // 8 words x 8 k-stripes
          ull d = 0;
          for (int kk = s; kk < nk; kk += 8)
            d |= tileRows[buf][newk[kk] * TRS + w];
          d |= __shfl_xor(d, 8);
          d |= __shfl_xor(d, 16);
          d |= __shfl_xor(d, 32);
          if (s == 0 && w > gi && w < TW) remvA[w] |= d;
        }
        if (done) break;
      }
      if (lane == 0) {
        kcLds = kc;
        if (kc >= TOPK2) doneLds = 1;
      }
    } else if (T + 1 < NT) {
      // ---- waves 1-3: stage tile T+1 + base removal over stable prefix ----
      const int tid3 = tid - 64;             // 0..191
      for (int idx = tid3; idx < TWn * 512; idx += 192) {
        int w = idx >> 9, row = idx & 511;
        int gr = G0n * 64 + row;
        ull v = (gr < TOPK1) ? mask[(size_t)(G0n + w) * TOPK1 + gr] : 0;
        tileRows[buf ^ 1][row * TRS + w] = v;
      }
      int w = tid3 & 7, stripe = tid3 >> 3;  // 24 stripes x 8 words
      ull acc = 0;
      if (w < TWn) {
        const ull* mw = mask + (size_t)(G0n + w) * TOPK1;
        int t = stripe;
        for (; t + 7 * 24 < kcStart; t += 8 * 24) {
          ull a0 = mw[klist[t          ]];
          ull a1 = mw[klist[t + 1 * 24]];
          ull a2 = mw[klist[t + 2 * 24]];
          ull a3 = mw[klist[t + 3 * 24]];
          ull a4 = mw[klist[t + 4 * 24]];
          ull a5 = mw[klist[t + 5 * 24]];
          ull a6 = mw[klist[t + 6 * 24]];
          ull a7 = mw[klist[t + 7 * 24]];
          acc |= ((a0 | a1) | (a2 | a3)) | ((a4 | a5) | (a6 | a7));
        }
        for (; t < kcStart; t += 24) acc |= mw[klist[t]];
      }
      remvPart[stripe][w] = acc;
    }
    __syncthreads();
    if (doneLds) break;
    if (T + 1 >= NT) break;
    // ---- delta removal: rows kept during tile T, at T+1's words (wave0) ----
    const int kcNew = kcLds;
    if (wave == 0) {
      int w = lane & 7, s = lane >> 3;       // 8 words x 8 k-stripes
      ull d = 0;
      if (w < TWn) {
        const ull* mw = mask + (size_t)(G0n + w) * TOPK1;
        for (int kk = kcStart + s; kk < kcNew; kk += 8) d |= mw[klist[kk]];
      }
      remvPart[24 + s][w] = d;
    }
    __syncthreads();
    if (tid < NTILE) {
      ull r = 0;
#pragma unroll
      for (int s2 = 0; s2 < 32; ++s2) r |= remvPart[s2][tid];
      remvA[tid] = r;
    }
    __syncthreads();
    buf ^= 1;
  }
}

// ---------------- compact kept boxes, sigmoid scores, write output ---------
__global__ __launch_bounds__(256) void finalize_kernel(const ull* __restrict__ keepwords,
                                                       const double* __restrict__ sBox,
                                                       const double* __restrict__ sLog,
                                                       float* __restrict__ out) {
  __shared__ int pref[WORDS];
  int t = threadIdx.x;
  if (t == 0) {
    int s = 0;
    for (int w = 0; w < WORDS; ++w) {
      pref[w] = s;
      s += __popcll(keepwords[w]);
    }
  }
  __syncthreads();
  if (t < WORDS) {
    ull kb = keepwords[t];
    int base = pref[t];
    while (kb) {
      int b = __ffsll((long long)kb) - 1;
      kb &= kb - 1;
      if (base < TOPK2) {
        int i = t * 64 + b;
        out[base * 4 + 0] = (float)sBox[(size_t)i * 4 + 0];
        out[base * 4 + 1] = (float)sBox[(size_t)i * 4 + 1];
        out[base * 4 + 2] = (float)sBox[(size_t)i * 4 + 2];
        out[base * 4 + 3] = (float)sBox[(size_t)i * 4 + 3];
        double L = sLog[i];
        out[TOPK2 * 4 + base] = (float)(1.0 / (1.0 + exp(-L)));
      }
      ++base;
    }
  }
}

// ---------------------------------------------------------------------------
extern "C" void kernel_launch(void* const* d_in, const int* in_sizes, int n_in,
                              void* d_out, int out_size, void* d_ws, size_t ws_size,
                              hipStream_t stream) {
  // inputs: 0 image(unused) 1 feat 2 rpn_w 3 rpn_b 4 cls_w 5 cls_b 6 box_w 7 box_b
  const float* feat  = (const float*)d_in[1];
  const float* rpn_w = (const float*)d_in[2];
  const float* rpn_b = (const float*)d_in[3];
  const float* cls_w = (const float*)d_in[4];
  const float* cls_b = (const float*)d_in[5];
  const float* box_w = (const float*)d_in[6];
  const float* box_b = (const float*)d_in[7];
  float* out = (float*)d_out;

  // workspace layout (bytes, all 16B aligned); total ~34.44 MB
  char* ws = (char*)d_ws;
  double* part     = (double*)(ws);                 // 2*512*2500*8 = 20,480,000
  double* logits   = (double*)(ws + 20480000);      // 22500*8     =    180,000
  double* boxesAll = (double*)(ws + 20660000);      // 22500*4*8   =    720,000
  int*    ranks    = (int*)   (ws + 21380000);      // 22500*4     =     90,000
  double* sBox     = (double*)(ws + 21470000);      // 10000*4*8   =    320,000
  double* sLog     = (double*)(ws + 21790000);      // 10000*8     =     80,000
  ull*    mask     = (ull*)   (ws + 21870000);      // 157*10000*8 = 12,560,000
  ull*    keepw    = (ull*)   (ws + 34430000);      // 157*8       =      1,256
  // mask region is multiply-overlaid (all stream-ordered, lifetimes disjoint):
  //   wT (4608*512*4 = 9,437,184 B): written by wtrans, read by conv_gemm,
  //      dead after conv_gemm completes.
  //   headsc (2500*48*8 = 960,000 B): written by heads_mm (after conv),
  //      read by decode_kernel, dead before iou_mask writes mask.
  float*  wT       = (float*) (ws + 21870000);
  double* headsc   = (double*)(ws + 21870000);

  hipMemsetAsync(d_out, 0, (TOPK2 * 4 + TOPK2) * sizeof(float), stream);
  hipMemsetAsync(ranks, 0, NBOX * sizeof(int), stream);
  hipMemsetAsync(keepw, 0, WORDS * sizeof(ull), stream);  // early-exit tail

  wtrans<<<dim3(128, 8), 256, 0, stream>>>(rpn_w, wT);
  conv_gemm<<<dim3(80, 8, 2), 256, 0, stream>>>(feat, wT, part);
  heads_mm<<<dim3(40, 12), 256, 0, stream>>>(part, rpn_b, cls_w, box_w, headsc);
  decode_kernel<<<88, 256, 0, stream>>>(headsc, cls_b, box_b, logits, boxesAll,
                                        out + TOPK2 * 5);
  rank_count<<<dim3(88, 11), 256, 0, stream>>>(logits, ranks);
  scatter_topk<<<88, 256, 0, stream>>>(logits, boxesAll, ranks, sLog, sBox);
  iou_mask<<<dim3(WORDS, 40), 256, 0, stream>>>(sBox, mask);
  nms_scan<<<1, 256, 0, stream>>>(mask, keepw);
  finalize_kernel<<<1, 256, 0, stream>>>(keepw, sBox, sLog, out);
}

// Round 10
// 800.332 us; speedup vs baseline: 1.0656x; 1.0656x over previous
//
#include <hip/hip_runtime.h>
#include <cstdint>
#include <cstddef>

// ---------------------------------------------------------------------------
// RPN pipeline, fp64-accurate (ordering-critical: top-k rank + NMS decisions).
// fp32 inputs; all reductions accumulate in double (fp32*fp32 exact in f64).
// R18: full revert to the R14 configuration (measured 804.1us). The R16/R17
// nms_scan/iou_mask experiments regressed (+17, +32us): nms_scan cost is
// INVARIANT (~270-300us) under mask layout, barrier count, and pipelining --
// it is a dependent-latency chain on one CU. Re-anchoring at the proven best.
// ---------------------------------------------------------------------------

typedef unsigned long long ull;
typedef double d4 __attribute__((ext_vector_type(4)));

#define NANCH 9
#define NPIX  2500      // 50*50
#define CIN   512
#define COUT  512
#define KTOT  4608      // 512*9
#define KSEG  2304      // KTOT/2
#define NBOX  22500     // 2500*9
#define TOPK1 10000
#define TOPK2 2000
#define WORDS 157       // ceil(10000/64)
#define NHEAD 45        // 9 cls + 36 box channels
#define HPAD  48        // padded per-pixel stride for head scratch

// ---------------- one-shot weight transpose to tap-major k' ---------------
// wT[(tap*512+ci)*512 + co] = w[co*4608 + ci*9 + tap].  LDS-tiled so both
// global reads and writes are coalesced.  ~2.4M floats, few us.
__global__ __launch_bounds__(256) void wtrans(const float* __restrict__ w,
                                              float* __restrict__ wT) {
  __shared__ float t[36][65];
  const int ci0 = blockIdx.x * 4;    // 4 ci per block -> 36 (tap,ci) rows
  const int co0 = blockIdx.y * 64;
  const int tid = threadIdx.x;
  // read: thread (co_l, cq) reads 9 taps contiguously for one (co,ci)
  const int co_l = tid >> 2, cq = tid & 3;
  const float* src = w + (size_t)(co0 + co_l) * KTOT + (ci0 + cq) * 9;
#pragma unroll
  for (int r = 0; r < 9; ++r) t[r * 4 + cq][co_l] = src[r];
  __syncthreads();
  // write: thread (co_w, rw0) writes 9 rows, coalesced along co
  const int co_w = tid & 63, rw0 = tid >> 6;
#pragma unroll
  for (int m = 0; m < 9; ++m) {
    int rw = rw0 + 4 * m;            // 0..35
    int tap = rw >> 2, cqq = rw & 3;
    wT[((size_t)tap * 512 + ci0 + cqq) * 512 + co0 + co_w] = t[rw][co_w];
  }
}

// ---------------- conv 3x3 as implicit-im2col GEMM, f64 MFMA ---------------
// R14: wave-count x cheap-staging. Tap-major k' (A-tile = shifted masked
// coalesced copy of feat; B coalesced from wT) + 256-thread blocks, grid
// (80,8,2)=1280 = 5 blocks/CU -> 20 waves/CU. 268-271us, MfmaUtil ~61%
// (f64 MFMA floor is 154us).
__global__ __launch_bounds__(256, 5) void conv_gemm(const float* __restrict__ feat,
                                                    const float* __restrict__ wT,
                                                    double* __restrict__ part) {
  const int p0  = blockIdx.x * 32;
  const int co0 = blockIdx.y * 64;
  const int z   = blockIdx.z;
  const int kseg0 = z * KSEG;
  __shared__ float As[2][32][40];   // [buf][k][p]  f32, stride 40 (==8 mod 32)
  __shared__ float Bs[2][32][72];   // [buf][k][co] f32, stride 72 (==8 mod 32)
  const int tid  = threadIdx.x;      // 0..255
  const int lane = tid & 63;
  const int wave = tid >> 6;         // 0..3
  const int quad = lane >> 4;
  const int l16  = lane & 15;
  const int wp = (wave & 1) * 16;    // wave p offset in tile
  const int wc = (wave >> 1) * 32;   // wave co offset in tile
  // A loader: thread = (pixel plA, k-row kAr in 0..7); covers rows kAr+8*jj
  const int plA = tid & 31, kAr = tid >> 5;
  const int pB = p0 + plA;
  const int py = pB / 50, px = pB - py * 50;
  // B loader: thread = (co lane coB, k-row kBr in 0..3); covers rows kBr+4*s
  const int coB = tid & 63, kBr = tid >> 6;

  // ---- layout probe: learn the C/D register->(m,n) mapping ----
  int pmap[4];
  {
    double av_p = (quad == 0) ? (double)(l16 + 1) : (quad == 1 ? 1.0 : 0.0);
    double bv_p = (quad == 0) ? 1.0 : (quad == 1 ? (double)(1000 * (l16 + 1)) : 0.0);
    d4 dp = (d4){0.0, 0.0, 0.0, 0.0};
    dp = __builtin_amdgcn_mfma_f64_16x16x4f64(av_p, bv_p, dp, 0, 0, 0);
#pragma unroll
    for (int r = 0; r < 4; ++r) {
      int iv = (int)(dp[r] + 0.5);
      int mm = iv % 1000 - 1;   // p-id within the 16 block
      int nn = iv / 1000 - 1;   // co-id within the 16 block
      pmap[r] = (mm & 255) | (nn << 8);
    }
  }

  d4 acc[2];
#pragma unroll
  for (int i = 0; i < 2; ++i) acc[i] = (d4){0.0, 0.0, 0.0, 0.0};

  const int NCH = KSEG / 32;   // 72 chunks

  float fa[4], fb[8];

  // A loads for chunk cc: tap constant within chunk -> shifted masked copy
  auto loadA = [&](int cc) {
    int kk0 = kseg0 + cc * 32;
    int tap = kk0 >> 9;             // 0..8
    int ci0 = kk0 & 511;
    int ky = (tap * 11) >> 5;       // tap/3 for tap<9
    int kx = tap - 3 * ky;
    int yy = py + ky - 1, xx = px + kx - 1;
    bool valid = (pB < NPIX) && (yy >= 0) && (yy < 50) && (xx >= 0) && (xx < 50);
    int off = valid ? ((ci0 + kAr) * NPIX + yy * 50 + xx) : 0;
#pragma unroll
    for (int jj = 0; jj < 4; ++jj) {
      float v = feat[off + jj * 8 * NPIX];   // rows kAr+8*jj (in-bounds always)
      fa[jj] = valid ? v : 0.0f;
    }
  };
  // B loads for chunk cc: coalesced rows of wT
  auto loadB = [&](int cc) {
    const float* src = wT + (size_t)(kseg0 + cc * 32 + kBr) * 512 + co0 + coB;
#pragma unroll
    for (int s = 0; s < 8; ++s) fb[s] = src[s * 4 * 512];  // rows kBr+4*s
  };

  // ---- prologue: stage chunk 0 into buf 0; prefetch chunk 1 into regs ----
  loadA(0);
  loadB(0);
#pragma unroll
  for (int jj = 0; jj < 4; ++jj) As[0][kAr + 8 * jj][plA] = fa[jj];
#pragma unroll
  for (int s = 0; s < 8; ++s) Bs[0][kBr + 4 * s][coB] = fb[s];
  loadA(1);
  loadB(1);
  __syncthreads();

  for (int c = 0; c < NCH; ++c) {
    const int buf = c & 1;
    // stage chunk c+1 into the other buffer (regs loaded last iteration)
    if (c + 1 < NCH) {
#pragma unroll
      for (int jj = 0; jj < 4; ++jj) As[buf ^ 1][kAr + 8 * jj][plA] = fa[jj];
#pragma unroll
      for (int s = 0; s < 8; ++s) Bs[buf ^ 1][kBr + 4 * s][coB] = fb[s];
    }
    // issue global loads for chunk c+2 (retire during the MFMA burst)
    if (c + 2 < NCH) {
      loadA(c + 2);
      loadB(c + 2);
    }
    // MFMA burst from buf: 8 k-steps x 2 tile-MFMAs (1 A read feeds 2)
#pragma unroll
    for (int kk = 0; kk < 32; kk += 4) {
      double av  = (double)As[buf][kk + quad][wp + l16];
      double bv0 = (double)Bs[buf][kk + quad][wc + l16];
      double bv1 = (double)Bs[buf][kk + quad][wc + 16 + l16];
      acc[0] = __builtin_amdgcn_mfma_f64_16x16x4f64(av, bv0, acc[0], 0, 0, 0);
      acc[1] = __builtin_amdgcn_mfma_f64_16x16x4f64(av, bv1, acc[1], 0, 0, 0);
    }
    __syncthreads();  // iter-c writes of buf^1 <-> iter-c+1 reads of buf^1
  }
  // epilogue: probe-decoded scatter
  double* basez = part + (size_t)z * COUT * NPIX;
#pragma unroll
  for (int cj = 0; cj < 2; ++cj) {
#pragma unroll
    for (int r = 0; r < 4; ++r) {
      int mm = pmap[r] & 255, nn = pmap[r] >> 8;
      int p  = p0 + wp + mm;
      int co = co0 + wc + cj * 16 + nn;
      if (p < NPIX) basez[(size_t)co * NPIX + p] = acc[cj][r];
    }
  }
}

// ---------------- heads stage 1: output-parallel 1x1-conv GEMM -------------
// R14 (40,12)-grid version. R15's single-pass rewrite collapsed concurrency
// to 40 CUs (+110us); the 45x part re-reads are L3-resident and latency-
// hidden by 1920 waves. thread = (pixel, head-channel o); each wave has a
// wave-uniform o (scalar weight loads), lanes cover 64 px (coalesced).
// Summation order co=0..511 ascending -> numerics unchanged.
__global__ __launch_bounds__(256) void heads_mm(
    const double* __restrict__ part, const float* __restrict__ rpn_b,
    const float* __restrict__ cls_w, const float* __restrict__ box_w,
    double* __restrict__ headsc) {
  const int lane = threadIdx.x & 63;
  const int o = __builtin_amdgcn_readfirstlane(blockIdx.y * 4 + (threadIdx.x >> 6));
  if (o >= NHEAD) return;
  const int p = blockIdx.x * 64 + lane;
  const bool act = p < NPIX;
  const int pp = act ? p : 0;
  const float* wsel = (o < 9) ? (cls_w + (size_t)o * CIN)
                              : (box_w + (size_t)(o - 9) * CIN);
  const double* p0 = part + pp;
  const double* p1 = part + (size_t)COUT * NPIX + pp;
  double acc = 0.0;
#pragma unroll 4
  for (int co = 0; co < CIN; ++co) {
    double v = p0[(size_t)co * NPIX] + p1[(size_t)co * NPIX] + (double)rpn_b[co];
    v = v > 0.0 ? v : 0.0;
    acc += (double)wsel[co] * v;
  }
  if (act) headsc[(size_t)p * HPAD + o] = acc;
}

// ---------------- heads stage 2: bias + anchor decode + clamp --------------
__global__ __launch_bounds__(256) void decode_kernel(
    const double* __restrict__ headsc, const float* __restrict__ cls_b,
    const float* __restrict__ box_b, double* __restrict__ logits,
    double* __restrict__ boxesAll, float* __restrict__ out_cls) {
  int idx = blockIdx.x * blockDim.x + threadIdx.x;
  if (idx >= NBOX) return;
  int p = idx / 9, a = idx - p * 9;
  int y = p / 50, x = p - y * 50;
  double sx = 16.0 * (double)x, sy = 16.0 * (double)y;
  const double scs[3] = {128.0, 256.0, 512.0};
  const double ars[3] = {0.5, 1.0, 2.0};
  double ar = ars[a / 3], sc = scs[a - (a / 3) * 3];
  double hr = sqrt(ar), wr = 1.0 / hr;
  double wv = wr * sc, hv = hr * sc;
  // jnp.round == round-half-even == rint under default rounding mode
  double bx0 = rint(-wv * 0.5), by0 = rint(-hv * 0.5);
  double bx1 = rint(wv * 0.5), by1 = rint(hv * 0.5);
  double a0 = sx + bx0, a1 = sy + by0, a2 = sx + bx1, a3 = sy + by1;
  double wA = a2 - a0, hA = a3 - a1;
  double cx = a0 + 0.5 * wA, cy = a1 + 0.5 * hA;
  const double* hp = headsc + (size_t)p * HPAD;
  double dx = hp[9 + a * 4 + 0] + (double)box_b[a * 4 + 0];
  double dy = hp[9 + a * 4 + 1] + (double)box_b[a * 4 + 1];
  double dw = hp[9 + a * 4 + 2] + (double)box_b[a * 4 + 2];
  double dh = hp[9 + a * 4 + 3] + (double)box_b[a * 4 + 3];
  double pcx = wA * dx + cx, pcy = hA * dy + cy;
  double pw = exp(dw) * wA, ph = exp(dh) * hA;
  double b0 = pcx - 0.5 * pw, b1 = pcy - 0.5 * ph;
  double b2 = pcx + 0.5 * pw, b3 = pcy + 0.5 * ph;
  b0 = fmin(fmax(b0, 0.0), 800.0);
  b1 = fmin(fmax(b1, 0.0), 800.0);
  b2 = fmin(fmax(b2, 0.0), 800.0);
  b3 = fmin(fmax(b3, 0.0), 800.0);
  boxesAll[(size_t)idx * 4 + 0] = b0;
  boxesAll[(size_t)idx * 4 + 1] = b1;
  boxesAll[(size_t)idx * 4 + 2] = b2;
  boxesAll[(size_t)idx * 4 + 3] = b3;
  double L = hp[a] + (double)cls_b[a];
  logits[idx] = L;
  out_cls[idx] = (float)L;
}

// ---------------- exact stable descending rank (== jax.lax.top_k order) ---
__global__ __launch_bounds__(256) void rank_count(const double* __restrict__ logits,
                                                  int* __restrict__ ranks) {
  __shared__ double Ls[2048];
  int i = blockIdx.x * 256 + threadIdx.x;
  int j0 = blockIdx.y * 2048;
  int jn = NBOX - j0;
  if (jn > 2048) jn = 2048;
  for (int t = threadIdx.x; t < jn; t += 256) Ls[t] = logits[j0 + t];
  __syncthreads();
  if (i >= NBOX) return;
  double Li = logits[i];
  int cnt = 0;
  for (int t = 0; t < jn; ++t) {
    double Lj = Ls[t];
    int j = j0 + t;
    cnt += (Lj > Li || (Lj == Li && j < i)) ? 1 : 0;
  }
  atomicAdd(&ranks[i], cnt);
}

__global__ __launch_bounds__(256) void scatter_topk(const double* __restrict__ logits,
                                                    const double* __restrict__ boxesAll,
                                                    const int* __restrict__ ranks,
                                                    double* __restrict__ sLog,
                                                    double* __restrict__ sBox) {
  int i = blockIdx.x * 256 + threadIdx.x;
  if (i >= NBOX) return;
  int r = ranks[i];
  if (r < TOPK1) {
    sLog[r] = logits[i];
    sBox[(size_t)r * 4 + 0] = boxesAll[(size_t)i * 4 + 0];
    sBox[(size_t)r * 4 + 1] = boxesAll[(size_t)i * 4 + 1];
    sBox[(size_t)r * 4 + 2] = boxesAll[(size_t)i * 4 + 2];
    sBox[(size_t)r * 4 + 3] = boxesAll[(size_t)i * 4 + 3];
  }
}

// ---------------- pairwise IoU suppression bitmask (upper triangle) --------
__global__ __launch_bounds__(256) void iou_mask(const double* __restrict__ sb,
                                                ull* __restrict__ mask) {
  const int it = blockIdx.x;
  const int wt = blockIdx.y;
  if (wt * 4 + 3 < it) return;  // block only needed for words >= i/64
  __shared__ double ib[64][4];
  __shared__ double jb[256][4];
  const int tid = threadIdx.x;
  {
    int ii = it * 64 + (tid >> 2);
    int d = tid & 3;
    ib[tid >> 2][d] = (ii < TOPK1) ? sb[(size_t)ii * 4 + d] : 0.0;
  }
  for (int t = tid; t < 1024; t += 256) {
    int jj = wt * 256 + (t >> 2);
    jb[t >> 2][t & 3] = (jj < TOPK1) ? sb[(size_t)jj * 4 + (t & 3)] : 0.0;
  }
  __syncthreads();
  const int il = tid & 63, wl = tid >> 6;
  const int i = it * 64 + il;
  const int word = wt * 4 + wl;
  if (i >= TOPK1 || word >= WORDS || word < (i >> 6)) return;
  const double x0 = ib[il][0], y0 = ib[il][1], x1 = ib[il][2], y1 = ib[il][3];
  const double areai = (x1 - x0) * (y1 - y0);
  ull bits = 0;
  const int jbase = word * 64;
  for (int b = 0; b < 64; ++b) {
    int j = jbase + b;
    if (j <= i || j >= TOPK1) continue;
    int jl = wl * 64 + b;
    double u0 = jb[jl][0], u1 = jb[jl][1], u2 = jb[jl][2], u3 = jb[jl][3];
    double xl = fmax(x0, u0), yt = fmax(y0, u1);
    double xr = fmin(x1, u2), yb = fmin(y1, u3);
    double iw = xr - xl, ih = yb - yt;
    iw = iw > 0.0 ? iw : 0.0;
    ih = ih > 0.0 ? ih : 0.0;
    double inter = iw * ih;
    double aj = (u2 - u0) * (u3 - u1);
    double un = areai + aj - inter;
    // reference: inter/un > 0.7 (0/0 -> NaN -> false). Multiply form matches.
    if (inter > 0.7 * un) bits |= 1ull << b;
  }
  mask[(size_t)i * WORDS + word] = bits;
}

// ---------------- tiled greedy-NMS scan, LDS-resident tile -----------------
#define NTILE 8
#define TRS   10    // padded ull stride for tileRows (8 words + 2 pad)
#define KCAP  2112

__global__ __launch_bounds__(256) void nms_scan(const ull* __restrict__ mask,
                                                ull* __restrict__ keepwords) {
  __shared__ ull tileRows[512 * TRS];        // 40,960 B
  __shared__ int klist[KCAP];                // kept global indices (rank order)
  __shared__ ull remvPart[32][NTILE + 1];    // column-OR partials
  __shared__ unsigned int remv32[NTILE * 2]; // removal words (lo/hi pairs)
  __shared__ int newk[64];                   // this group's kept local rows
  __shared__ int kcLds, nkLds, doneLds;
  const int tid = threadIdx.x;
  const int lane = tid & 63;
  const int wave = tid >> 6;
  if (tid == 0) { kcLds = 0; nkLds = 0; doneLds = 0; }
  __syncthreads();

  for (int T = 0; T < (WORDS + NTILE - 1) / NTILE; ++T) {
    const int G0 = T * NTILE;
    const int TW = (WORDS - G0 < NTILE) ? (WORDS - G0) : NTILE;
    const int kc0 = kcLds;
    // ---- Phase A1: stage tile rows (512 x TW words) into LDS ----
#pragma unroll
    for (int pass = 0; pass < 8; ++pass) {
      int lr = pass * 64 + (tid >> 2);   // local row 0..511
      int w  = (tid & 3) * 2;            // word pair
      int gr = G0 * 64 + lr;             // global row
      ull v0 = 0, v1 = 0;
      if (gr < TOPK1) {
        const ull* row = mask + (size_t)gr * WORDS + G0;
        if (w < TW)     v0 = row[w];
        if (w + 1 < TW) v1 = row[w + 1];
      }
      tileRows[lr * TRS + w]     = v0;
      tileRows[lr * TRS + w + 1] = v1;
    }
    // ---- Phase A2: base removal words = OR over previously-kept rows ----
    {
      int w = tid & 7, stripe = tid >> 3;   // 32 stripes x 8 words
      ull acc = 0;
      if (w < TW) {
        int t = stripe;
        for (; t + 224 < kc0; t += 256) {
          ull a0 = mask[(size_t)klist[t      ] * WORDS + G0 + w];
          ull a1 = mask[(size_t)klist[t +  32] * WORDS + G0 + w];
          ull a2 = mask[(size_t)klist[t +  64] * WORDS + G0 + w];
          ull a3 = mask[(size_t)klist[t +  96] * WORDS + G0 + w];
          ull a4 = mask[(size_t)klist[t + 128] * WORDS + G0 + w];
          ull a5 = mask[(size_t)klist[t + 160] * WORDS + G0 + w];
          ull a6 = mask[(size_t)klist[t + 192] * WORDS + G0 + w];
          ull a7 = mask[(size_t)klist[t + 224] * WORDS + G0 + w];
          acc |= ((a0 | a1) | (a2 | a3)) | ((a4 | a5) | (a6 | a7));
        }
        for (; t < kc0; t += 32) acc |= mask[(size_t)klist[t] * WORDS + G0 + w];
      }
      remvPart[stripe][w] = acc;
    }
    __syncthreads();
    if (tid < NTILE) {
      ull r = 0;
#pragma unroll
      for (int s = 0; s < 32; ++s) r |= remvPart[s][tid];
      remv32[tid * 2]     = (unsigned int)r;
      remv32[tid * 2 + 1] = (unsigned int)(r >> 32);
    }
    __syncthreads();
    // ---- Phase B: sequential resolve of the tile's groups (LDS only) ----
    for (int gi = 0; gi < TW; ++gi) {
      const int g = G0 + gi;
      if (wave == 0) {
        ull cur = ((ull)remv32[gi * 2 + 1] << 32) | remv32[gi * 2];
        unsigned int clo = __builtin_amdgcn_readfirstlane((unsigned int)cur);
        unsigned int chi = __builtin_amdgcn_readfirstlane((unsigned int)(cur >> 32));
        cur = ((ull)chi << 32) | clo;
        ull mrow = tileRows[(gi * 64 + lane) * TRS + gi];
        const unsigned int ml = (unsigned int)mrow;
        const unsigned int mh = (unsigned int)(mrow >> 32);
        const ull validm = (g == WORDS - 1) ? 0xFFFFull : ~0ull;
        ull rem = (~cur) & validm;
        while (rem) {
          int b = __ffsll((long long)rem) - 1;
          b = __builtin_amdgcn_readfirstlane(b);
          ull m = ((ull)(unsigned int)__builtin_amdgcn_readlane((int)mh, b) << 32) |
                  (unsigned int)__builtin_amdgcn_readlane((int)ml, b);
          cur |= m;
          ull above = (b == 63) ? 0ull : (~0ull << (b + 1));
          rem = (~cur) & rem & above;
        }
        ull kb = (~cur) & validm;
        if (lane == 0) keepwords[g] = kb;
        int kc = kcLds;
        if ((kb >> lane) & 1ull) {
          int ofs = __popcll(lane ? (kb & ((1ull << lane) - 1ull)) : 0ull);
          klist[kc + ofs] = g * 64 + lane;
          newk[ofs] = gi * 64 + lane;   // local row index for FU
        }
        if (lane == 0) {
          int nk = __popcll(kb);
          nkLds = nk;
          kcLds = kc + nk;
          doneLds = (kc + nk >= TOPK2) ? 1 : 0;
        }
      }
      __syncthreads();
      if (doneLds) break;
      // forward-update remaining tile words with newly kept rows (LDS only)
      if (gi + 1 < TW) {
        int w = tid & 7, k0 = tid >> 3;
        int nk = nkLds;
        if (w > gi && w < TW) {
          ull acc = 0;
          for (int kk = k0; kk < nk; kk += 32) acc |= tileRows[newk[kk] * TRS + w];
          if (acc) {
            atomicOr(&remv32[w * 2], (unsigned int)acc);
            atomicOr(&remv32[w * 2 + 1], (unsigned int)(acc >> 32));
          }
        }
      }
      __syncthreads();
    }
    if (doneLds) break;
  }
}

// ---------------- compact kept boxes, sigmoid scores, write output ---------
__global__ __launch_bounds__(256) void finalize_kernel(const ull* __restrict__ keepwords,
                                                       const double* __restrict__ sBox,
                                                       const double* __restrict__ sLog,
                                                       float* __restrict__ out) {
  __shared__ int pref[WORDS];
  int t = threadIdx.x;
  if (t == 0) {
    int s = 0;
    for (int w = 0; w < WORDS; ++w) {
      pref[w] = s;
      s += __popcll(keepwords[w]);
    }
  }
  __syncthreads();
  if (t < WORDS) {
    ull kb = keepwords[t];
    int base = pref[t];
    while (kb) {
      int b = __ffsll((long long)kb) - 1;
      kb &= kb - 1;
      if (base < TOPK2) {
        int i = t * 64 + b;
        out[base * 4 + 0] = (float)sBox[(size_t)i * 4 + 0];
        out[base * 4 + 1] = (float)sBox[(size_t)i * 4 + 1];
        out[base * 4 + 2] = (float)sBox[(size_t)i * 4 + 2];
        out[base * 4 + 3] = (float)sBox[(size_t)i * 4 + 3];
        double L = sLog[i];
        out[TOPK2 * 4 + base] = (float)(1.0 / (1.0 + exp(-L)));
      }
      ++base;
    }
  }
}

// ---------------------------------------------------------------------------
extern "C" void kernel_launch(void* const* d_in, const int* in_sizes, int n_in,
                              void* d_out, int out_size, void* d_ws, size_t ws_size,
                              hipStream_t stream) {
  // inputs: 0 image(unused) 1 feat 2 rpn_w 3 rpn_b 4 cls_w 5 cls_b 6 box_w 7 box_b
  const float* feat  = (const float*)d_in[1];
  const float* rpn_w = (const float*)d_in[2];
  const float* rpn_b = (const float*)d_in[3];
  const float* cls_w = (const float*)d_in[4];
  const float* cls_b = (const float*)d_in[5];
  const float* box_w = (const float*)d_in[6];
  const float* box_b = (const float*)d_in[7];
  float* out = (float*)d_out;

  // workspace layout (bytes, all 16B aligned); total ~34.44 MB
  char* ws = (char*)d_ws;
  double* part     = (double*)(ws);                 // 2*512*2500*8 = 20,480,000
  double* logits   = (double*)(ws + 20480000);      // 22500*8     =    180,000
  double* boxesAll = (double*)(ws + 20660000);      // 22500*4*8   =    720,000
  int*    ranks    = (int*)   (ws + 21380000);      // 22500*4     =     90,000
  double* sBox     = (double*)(ws + 21470000);      // 10000*4*8   =    320,000
  double* sLog     = (double*)(ws + 21790000);      // 10000*8     =     80,000
  ull*    mask     = (ull*)   (ws + 21870000);      // 10000*157*8 = 12,560,000
  ull*    keepw    = (ull*)   (ws + 34430000);      // 157*8       =      1,256
  // mask region is multiply-overlaid (all stream-ordered, lifetimes disjoint):
  //   wT (4608*512*4 = 9,437,184 B): written by wtrans, read by conv_gemm,
  //      dead after conv_gemm completes.
  //   headsc (2500*48*8 = 960,000 B): written by heads_mm (after conv),
  //      read by decode_kernel, dead before iou_mask writes mask.
  float*  wT       = (float*) (ws + 21870000);
  double* headsc   = (double*)(ws + 21870000);

  hipMemsetAsync(d_out, 0, (TOPK2 * 4 + TOPK2) * sizeof(float), stream);
  hipMemsetAsync(ranks, 0, NBOX * sizeof(int), stream);
  hipMemsetAsync(keepw, 0, WORDS * sizeof(ull), stream);  // early-exit tail

  wtrans<<<dim3(128, 8), 256, 0, stream>>>(rpn_w, wT);
  conv_gemm<<<dim3(80, 8, 2), 256, 0, stream>>>(feat, wT, part);
  heads_mm<<<dim3(40, 12), 256, 0, stream>>>(part, rpn_b, cls_w, box_w, headsc);
  decode_kernel<<<88, 256, 0, stream>>>(headsc, cls_b, box_b, logits, boxesAll,
                                        out + TOPK2 * 5);
  rank_count<<<dim3(88, 11), 256, 0, stream>>>(logits, ranks);
  scatter_topk<<<88, 256, 0, stream>>>(logits, boxesAll, ranks, sLog, sBox);
  iou_mask<<<dim3(WORDS, 40), 256, 0, stream>>>(sBox, mask);
  nms_scan<<<1, 256, 0, stream>>>(mask, keepw);
  finalize_kernel<<<1, 256, 0, stream>>>(keepw, sBox, sLog, out);
}

// Round 11
// 772.589 us; speedup vs baseline: 1.1038x; 1.0359x over previous
//
#include <hip/hip_runtime.h>
#include <cstdint>
#include <cstddef>

// ---------------------------------------------------------------------------
// RPN pipeline, fp64-accurate (ordering-critical: top-k rank + NMS decisions).
// fp32 inputs; all reductions accumulate in double (fp32*fp32 exact in f64).
// R18 re-anchored at the R14 config (measured 800.3us). R19 targets the
// unprofiled tail: heads_mm streamed part 45x (921MB L3); now LDS-shared.
// ---------------------------------------------------------------------------

typedef unsigned long long ull;
typedef double d4 __attribute__((ext_vector_type(4)));

#define NANCH 9
#define NPIX  2500      // 50*50
#define CIN   512
#define COUT  512
#define KTOT  4608      // 512*9
#define KSEG  2304      // KTOT/2
#define NBOX  22500     // 2500*9
#define TOPK1 10000
#define TOPK2 2000
#define WORDS 157       // ceil(10000/64)
#define NHEAD 45        // 9 cls + 36 box channels
#define HPAD  48        // padded per-pixel stride for head scratch

// ---------------- one-shot weight transpose to tap-major k' ---------------
// wT[(tap*512+ci)*512 + co] = w[co*4608 + ci*9 + tap].  LDS-tiled so both
// global reads and writes are coalesced.  ~2.4M floats, few us.
__global__ __launch_bounds__(256) void wtrans(const float* __restrict__ w,
                                              float* __restrict__ wT) {
  __shared__ float t[36][65];
  const int ci0 = blockIdx.x * 4;    // 4 ci per block -> 36 (tap,ci) rows
  const int co0 = blockIdx.y * 64;
  const int tid = threadIdx.x;
  // read: thread (co_l, cq) reads 9 taps contiguously for one (co,ci)
  const int co_l = tid >> 2, cq = tid & 3;
  const float* src = w + (size_t)(co0 + co_l) * KTOT + (ci0 + cq) * 9;
#pragma unroll
  for (int r = 0; r < 9; ++r) t[r * 4 + cq][co_l] = src[r];
  __syncthreads();
  // write: thread (co_w, rw0) writes 9 rows, coalesced along co
  const int co_w = tid & 63, rw0 = tid >> 6;
#pragma unroll
  for (int m = 0; m < 9; ++m) {
    int rw = rw0 + 4 * m;            // 0..35
    int tap = rw >> 2, cqq = rw & 3;
    wT[((size_t)tap * 512 + ci0 + cqq) * 512 + co0 + co_w] = t[rw][co_w];
  }
}

// ---------------- conv 3x3 as implicit-im2col GEMM, f64 MFMA ---------------
// R14: wave-count x cheap-staging. Tap-major k' (A-tile = shifted masked
// coalesced copy of feat; B coalesced from wT) + 256-thread blocks, grid
// (80,8,2)=1280 = 5 blocks/CU -> 20 waves/CU. 268-271us, MfmaUtil ~61%
// (f64 MFMA floor is 154us).
__global__ __launch_bounds__(256, 5) void conv_gemm(const float* __restrict__ feat,
                                                    const float* __restrict__ wT,
                                                    double* __restrict__ part) {
  const int p0  = blockIdx.x * 32;
  const int co0 = blockIdx.y * 64;
  const int z   = blockIdx.z;
  const int kseg0 = z * KSEG;
  __shared__ float As[2][32][40];   // [buf][k][p]  f32, stride 40 (==8 mod 32)
  __shared__ float Bs[2][32][72];   // [buf][k][co] f32, stride 72 (==8 mod 32)
  const int tid  = threadIdx.x;      // 0..255
  const int lane = tid & 63;
  const int wave = tid >> 6;         // 0..3
  const int quad = lane >> 4;
  const int l16  = lane & 15;
  const int wp = (wave & 1) * 16;    // wave p offset in tile
  const int wc = (wave >> 1) * 32;   // wave co offset in tile
  // A loader: thread = (pixel plA, k-row kAr in 0..7); covers rows kAr+8*jj
  const int plA = tid & 31, kAr = tid >> 5;
  const int pB = p0 + plA;
  const int py = pB / 50, px = pB - py * 50;
  // B loader: thread = (co lane coB, k-row kBr in 0..3); covers rows kBr+4*s
  const int coB = tid & 63, kBr = tid >> 6;

  // ---- layout probe: learn the C/D register->(m,n) mapping ----
  int pmap[4];
  {
    double av_p = (quad == 0) ? (double)(l16 + 1) : (quad == 1 ? 1.0 : 0.0);
    double bv_p = (quad == 0) ? 1.0 : (quad == 1 ? (double)(1000 * (l16 + 1)) : 0.0);
    d4 dp = (d4){0.0, 0.0, 0.0, 0.0};
    dp = __builtin_amdgcn_mfma_f64_16x16x4f64(av_p, bv_p, dp, 0, 0, 0);
#pragma unroll
    for (int r = 0; r < 4; ++r) {
      int iv = (int)(dp[r] + 0.5);
      int mm = iv % 1000 - 1;   // p-id within the 16 block
      int nn = iv / 1000 - 1;   // co-id within the 16 block
      pmap[r] = (mm & 255) | (nn << 8);
    }
  }

  d4 acc[2];
#pragma unroll
  for (int i = 0; i < 2; ++i) acc[i] = (d4){0.0, 0.0, 0.0, 0.0};

  const int NCH = KSEG / 32;   // 72 chunks

  float fa[4], fb[8];

  // A loads for chunk cc: tap constant within chunk -> shifted masked copy
  auto loadA = [&](int cc) {
    int kk0 = kseg0 + cc * 32;
    int tap = kk0 >> 9;             // 0..8
    int ci0 = kk0 & 511;
    int ky = (tap * 11) >> 5;       // tap/3 for tap<9
    int kx = tap - 3 * ky;
    int yy = py + ky - 1, xx = px + kx - 1;
    bool valid = (pB < NPIX) && (yy >= 0) && (yy < 50) && (xx >= 0) && (xx < 50);
    int off = valid ? ((ci0 + kAr) * NPIX + yy * 50 + xx) : 0;
#pragma unroll
    for (int jj = 0; jj < 4; ++jj) {
      float v = feat[off + jj * 8 * NPIX];   // rows kAr+8*jj (in-bounds always)
      fa[jj] = valid ? v : 0.0f;
    }
  };
  // B loads for chunk cc: coalesced rows of wT
  auto loadB = [&](int cc) {
    const float* src = wT + (size_t)(kseg0 + cc * 32 + kBr) * 512 + co0 + coB;
#pragma unroll
    for (int s = 0; s < 8; ++s) fb[s] = src[s * 4 * 512];  // rows kBr+4*s
  };

  // ---- prologue: stage chunk 0 into buf 0; prefetch chunk 1 into regs ----
  loadA(0);
  loadB(0);
#pragma unroll
  for (int jj = 0; jj < 4; ++jj) As[0][kAr + 8 * jj][plA] = fa[jj];
#pragma unroll
  for (int s = 0; s < 8; ++s) Bs[0][kBr + 4 * s][coB] = fb[s];
  loadA(1);
  loadB(1);
  __syncthreads();

  for (int c = 0; c < NCH; ++c) {
    const int buf = c & 1;
    // stage chunk c+1 into the other buffer (regs loaded last iteration)
    if (c + 1 < NCH) {
#pragma unroll
      for (int jj = 0; jj < 4; ++jj) As[buf ^ 1][kAr + 8 * jj][plA] = fa[jj];
#pragma unroll
      for (int s = 0; s < 8; ++s) Bs[buf ^ 1][kBr + 4 * s][coB] = fb[s];
    }
    // issue global loads for chunk c+2 (retire during the MFMA burst)
    if (c + 2 < NCH) {
      loadA(c + 2);
      loadB(c + 2);
    }
    // MFMA burst from buf: 8 k-steps x 2 tile-MFMAs (1 A read feeds 2)
#pragma unroll
    for (int kk = 0; kk < 32; kk += 4) {
      double av  = (double)As[buf][kk + quad][wp + l16];
      double bv0 = (double)Bs[buf][kk + quad][wc + l16];
      double bv1 = (double)Bs[buf][kk + quad][wc + 16 + l16];
      acc[0] = __builtin_amdgcn_mfma_f64_16x16x4f64(av, bv0, acc[0], 0, 0, 0);
      acc[1] = __builtin_amdgcn_mfma_f64_16x16x4f64(av, bv1, acc[1], 0, 0, 0);
    }
    __syncthreads();  // iter-c writes of buf^1 <-> iter-c+1 reads of buf^1
  }
  // epilogue: probe-decoded scatter
  double* basez = part + (size_t)z * COUT * NPIX;
#pragma unroll
  for (int cj = 0; cj < 2; ++cj) {
#pragma unroll
    for (int r = 0; r < 4; ++r) {
      int mm = pmap[r] & 255, nn = pmap[r] >> 8;
      int p  = p0 + wp + mm;
      int co = co0 + wc + cj * 16 + nn;
      if (p < NPIX) basez[(size_t)co * NPIX + p] = acc[cj][r];
    }
  }
}

// ---------------- heads stage 1: LDS-shared 1x1-conv over part -------------
// R19: traffic fix with concurrency kept. The R14 version streamed part once
// PER CHANNEL (45x = 921MB of L3 traffic, >=65us floor). R15's 40-block
// single-pass fixed traffic but collapsed concurrency (+110us). Now grid
// (40 px-tiles, 6 channel-octets) = 240 blocks (~1/CU, 4 waves): per 32-co
// chunk all 256 threads cooperatively stage v = relu(part0+part1+bias) into
// LDS (coalesced, double-buffered, reg-prefetch of chunk c+2 like conv);
// each wave accumulates its 2 channels from LDS (weight reads wave-uniform
// scalar; v reads 2-way bank = free). Traffic 921 -> 123MB. Numerics
// BIT-IDENTICAL: per (p,o) the chain is still acc += w[co]*v, co = 0..511
// strictly ascending, v computed by the identical expression.
__global__ __launch_bounds__(256) void heads_mm(
    const double* __restrict__ part, const float* __restrict__ rpn_b,
    const float* __restrict__ cls_w, const float* __restrict__ box_w,
    double* __restrict__ headsc) {
  __shared__ double vt[2][32][66];   // [buf][co][px], 33.8 KB total
  const int tid  = threadIdx.x;
  const int lane = tid & 63;
  const int wave = tid >> 6;
  const int p0 = blockIdx.x * 64;
  const int p  = p0 + lane;
  const bool act = p < NPIX;
  const int ob = __builtin_amdgcn_readfirstlane(blockIdx.y * 8 + wave * 2);
  const int o0 = ob, o1 = ob + 1;                 // o1 may be invalid (>=45)
  auto wptr = [&](int o) {
    int oc = o < NHEAD ? o : NHEAD - 1;           // clamp: junk acc, not written
    return (oc < 9) ? cls_w + (size_t)oc * CIN
                    : box_w + (size_t)(oc - 9) * CIN;
  };
  const float* w0p = wptr(o0);
  const float* w1p = wptr(o1);

  // staging role: thread (px = tid&63, cr = tid>>6) covers rows cr+4*s
  const int pl = tid & 63, cr = tid >> 6;
  const int pp = (p0 + pl < NPIX) ? (p0 + pl) : 0;   // clamp (junk, unread)
  const int NCHK = CIN / 32;                         // 16 chunks

  double ra[8], rb[8];
  auto loadC = [&](int cb) {                         // issue chunk's loads
#pragma unroll
    for (int s = 0; s < 8; ++s) {
      int row = cb + cr + 4 * s;
      ra[s] = part[(size_t)row * NPIX + pp];
      rb[s] = part[(size_t)(row + COUT) * NPIX + pp];
    }
  };
  auto storeC = [&](int buf, int cb) {               // regs -> LDS (v computed)
#pragma unroll
    for (int s = 0; s < 8; ++s) {
      int rloc = cr + 4 * s;
      double v = ra[s] + rb[s] + (double)rpn_b[cb + rloc];
      vt[buf][rloc][pl] = v > 0.0 ? v : 0.0;
    }
  };

  double acc0 = 0.0, acc1 = 0.0;

  // prologue: stage chunk 0 into buf 0; prefetch chunk 1 into regs
  loadC(0);
  storeC(0, 0);
  loadC(32);
  __syncthreads();

  for (int c = 0; c < NCHK; ++c) {
    const int buf = c & 1;
    const int cb = c * 32;
    if (c + 1 < NCHK) storeC(buf ^ 1, cb + 32);      // regs from last iter
    if (c + 2 < NCHK) loadC(cb + 64);                // retire during compute
#pragma unroll 8
    for (int col = 0; col < 32; ++col) {
      double v = vt[buf][col][lane];
      acc0 += (double)w0p[cb + col] * v;
      acc1 += (double)w1p[cb + col] * v;
    }
    __syncthreads();   // iter-c writes of buf^1 <-> iter-c+1 reads of buf^1
  }
  if (act) {
    if (o0 < NHEAD) headsc[(size_t)p * HPAD + o0] = acc0;
    if (o1 < NHEAD) headsc[(size_t)p * HPAD + o1] = acc1;
  }
}

// ---------------- heads stage 2: bias + anchor decode + clamp --------------
__global__ __launch_bounds__(256) void decode_kernel(
    const double* __restrict__ headsc, const float* __restrict__ cls_b,
    const float* __restrict__ box_b, double* __restrict__ logits,
    double* __restrict__ boxesAll, float* __restrict__ out_cls) {
  int idx = blockIdx.x * blockDim.x + threadIdx.x;
  if (idx >= NBOX) return;
  int p = idx / 9, a = idx - p * 9;
  int y = p / 50, x = p - y * 50;
  double sx = 16.0 * (double)x, sy = 16.0 * (double)y;
  const double scs[3] = {128.0, 256.0, 512.0};
  const double ars[3] = {0.5, 1.0, 2.0};
  double ar = ars[a / 3], sc = scs[a - (a / 3) * 3];
  double hr = sqrt(ar), wr = 1.0 / hr;
  double wv = wr * sc, hv = hr * sc;
  // jnp.round == round-half-even == rint under default rounding mode
  double bx0 = rint(-wv * 0.5), by0 = rint(-hv * 0.5);
  double bx1 = rint(wv * 0.5), by1 = rint(hv * 0.5);
  double a0 = sx + bx0, a1 = sy + by0, a2 = sx + bx1, a3 = sy + by1;
  double wA = a2 - a0, hA = a3 - a1;
  double cx = a0 + 0.5 * wA, cy = a1 + 0.5 * hA;
  const double* hp = headsc + (size_t)p * HPAD;
  double dx = hp[9 + a * 4 + 0] + (double)box_b[a * 4 + 0];
  double dy = hp[9 + a * 4 + 1] + (double)box_b[a * 4 + 1];
  double dw = hp[9 + a * 4 + 2] + (double)box_b[a * 4 + 2];
  double dh = hp[9 + a * 4 + 3] + (double)box_b[a * 4 + 3];
  double pcx = wA * dx + cx, pcy = hA * dy + cy;
  double pw = exp(dw) * wA, ph = exp(dh) * hA;
  double b0 = pcx - 0.5 * pw, b1 = pcy - 0.5 * ph;
  double b2 = pcx + 0.5 * pw, b3 = pcy + 0.5 * ph;
  b0 = fmin(fmax(b0, 0.0), 800.0);
  b1 = fmin(fmax(b1, 0.0), 800.0);
  b2 = fmin(fmax(b2, 0.0), 800.0);
  b3 = fmin(fmax(b3, 0.0), 800.0);
  boxesAll[(size_t)idx * 4 + 0] = b0;
  boxesAll[(size_t)idx * 4 + 1] = b1;
  boxesAll[(size_t)idx * 4 + 2] = b2;
  boxesAll[(size_t)idx * 4 + 3] = b3;
  double L = hp[a] + (double)cls_b[a];
  logits[idx] = L;
  out_cls[idx] = (float)L;
}

// ---------------- exact stable descending rank (== jax.lax.top_k order) ---
__global__ __launch_bounds__(256) void rank_count(const double* __restrict__ logits,
                                                  int* __restrict__ ranks) {
  __shared__ double Ls[2048];
  int i = blockIdx.x * 256 + threadIdx.x;
  int j0 = blockIdx.y * 2048;
  int jn = NBOX - j0;
  if (jn > 2048) jn = 2048;
  for (int t = threadIdx.x; t < jn; t += 256) Ls[t] = logits[j0 + t];
  __syncthreads();
  if (i >= NBOX) return;
  double Li = logits[i];
  int cnt = 0;
  for (int t = 0; t < jn; ++t) {
    double Lj = Ls[t];
    int j = j0 + t;
    cnt += (Lj > Li || (Lj == Li && j < i)) ? 1 : 0;
  }
  atomicAdd(&ranks[i], cnt);
}

__global__ __launch_bounds__(256) void scatter_topk(const double* __restrict__ logits,
                                                    const double* __restrict__ boxesAll,
                                                    const int* __restrict__ ranks,
                                                    double* __restrict__ sLog,
                                                    double* __restrict__ sBox) {
  int i = blockIdx.x * 256 + threadIdx.x;
  if (i >= NBOX) return;
  int r = ranks[i];
  if (r < TOPK1) {
    sLog[r] = logits[i];
    sBox[(size_t)r * 4 + 0] = boxesAll[(size_t)i * 4 + 0];
    sBox[(size_t)r * 4 + 1] = boxesAll[(size_t)i * 4 + 1];
    sBox[(size_t)r * 4 + 2] = boxesAll[(size_t)i * 4 + 2];
    sBox[(size_t)r * 4 + 3] = boxesAll[(size_t)i * 4 + 3];
  }
}

// ---------------- pairwise IoU suppression bitmask (upper triangle) --------
__global__ __launch_bounds__(256) void iou_mask(const double* __restrict__ sb,
                                                ull* __restrict__ mask) {
  const int it = blockIdx.x;
  const int wt = blockIdx.y;
  if (wt * 4 + 3 < it) return;  // block only needed for words >= i/64
  __shared__ double ib[64][4];
  __shared__ double jb[256][4];
  const int tid = threadIdx.x;
  {
    int ii = it * 64 + (tid >> 2);
    int d = tid & 3;
    ib[tid >> 2][d] = (ii < TOPK1) ? sb[(size_t)ii * 4 + d] : 0.0;
  }
  for (int t = tid; t < 1024; t += 256) {
    int jj = wt * 256 + (t >> 2);
    jb[t >> 2][t & 3] = (jj < TOPK1) ? sb[(size_t)jj * 4 + (t & 3)] : 0.0;
  }
  __syncthreads();
  const int il = tid & 63, wl = tid >> 6;
  const int i = it * 64 + il;
  const int word = wt * 4 + wl;
  if (i >= TOPK1 || word >= WORDS || word < (i >> 6)) return;
  const double x0 = ib[il][0], y0 = ib[il][1], x1 = ib[il][2], y1 = ib[il][3];
  const double areai = (x1 - x0) * (y1 - y0);
  ull bits = 0;
  const int jbase = word * 64;
  for (int b = 0; b < 64; ++b) {
    int j = jbase + b;
    if (j <= i || j >= TOPK1) continue;
    int jl = wl * 64 + b;
    double u0 = jb[jl][0], u1 = jb[jl][1], u2 = jb[jl][2], u3 = jb[jl][3];
    double xl = fmax(x0, u0), yt = fmax(y0, u1);
    double xr = fmin(x1, u2), yb = fmin(y1, u3);
    double iw = xr - xl, ih = yb - yt;
    iw = iw > 0.0 ? iw : 0.0;
    ih = ih > 0.0 ? ih : 0.0;
    double inter = iw * ih;
    double aj = (u2 - u0) * (u3 - u1);
    double un = areai + aj - inter;
    // reference: inter/un > 0.7 (0/0 -> NaN -> false). Multiply form matches.
    if (inter > 0.7 * un) bits |= 1ull << b;
  }
  mask[(size_t)i * WORDS + word] = bits;
}

// ---------------- tiled greedy-NMS scan, LDS-resident tile -----------------
#define NTILE 8
#define TRS   10    // padded ull stride for tileRows (8 words + 2 pad)
#define KCAP  2112

__global__ __launch_bounds__(256) void nms_scan(const ull* __restrict__ mask,
                                                ull* __restrict__ keepwords) {
  __shared__ ull tileRows[512 * TRS];        // 40,960 B
  __shared__ int klist[KCAP];                // kept global indices (rank order)
  __shared__ ull remvPart[32][NTILE + 1];    // column-OR partials
  __shared__ unsigned int remv32[NTILE * 2]; // removal words (lo/hi pairs)
  __shared__ int newk[64];                   // this group's kept local rows
  __shared__ int kcLds, nkLds, doneLds;
  const int tid = threadIdx.x;
  const int lane = tid & 63;
  const int wave = tid >> 6;
  if (tid == 0) { kcLds = 0; nkLds = 0; doneLds = 0; }
  __syncthreads();

  for (int T = 0; T < (WORDS + NTILE - 1) / NTILE; ++T) {
    const int G0 = T * NTILE;
    const int TW = (WORDS - G0 < NTILE) ? (WORDS - G0) : NTILE;
    const int kc0 = kcLds;
    // ---- Phase A1: stage tile rows (512 x TW words) into LDS ----
#pragma unroll
    for (int pass = 0; pass < 8; ++pass) {
      int lr = pass * 64 + (tid >> 2);   // local row 0..511
      int w  = (tid & 3) * 2;            // word pair
      int gr = G0 * 64 + lr;             // global row
      ull v0 = 0, v1 = 0;
      if (gr < TOPK1) {
        const ull* row = mask + (size_t)gr * WORDS + G0;
        if (w < TW)     v0 = row[w];
        if (w + 1 < TW) v1 = row[w + 1];
      }
      tileRows[lr * TRS + w]     = v0;
      tileRows[lr * TRS + w + 1] = v1;
    }
    // ---- Phase A2: base removal words = OR over previously-kept rows ----
    {
      int w = tid & 7, stripe = tid >> 3;   // 32 stripes x 8 words
      ull acc = 0;
      if (w < TW) {
        int t = stripe;
        for (; t + 224 < kc0; t += 256) {
          ull a0 = mask[(size_t)klist[t      ] * WORDS + G0 + w];
          ull a1 = mask[(size_t)klist[t +  32] * WORDS + G0 + w];
          ull a2 = mask[(size_t)klist[t +  64] * WORDS + G0 + w];
          ull a3 = mask[(size_t)klist[t +  96] * WORDS + G0 + w];
          ull a4 = mask[(size_t)klist[t + 128] * WORDS + G0 + w];
          ull a5 = mask[(size_t)klist[t + 160] * WORDS + G0 + w];
          ull a6 = mask[(size_t)klist[t + 192] * WORDS + G0 + w];
          ull a7 = mask[(size_t)klist[t + 224] * WORDS + G0 + w];
          acc |= ((a0 | a1) | (a2 | a3)) | ((a4 | a5) | (a6 | a7));
        }
        for (; t < kc0; t += 32) acc |= mask[(size_t)klist[t] * WORDS + G0 + w];
      }
      remvPart[stripe][w] = acc;
    }
    __syncthreads();
    if (tid < NTILE) {
      ull r = 0;
#pragma unroll
      for (int s = 0; s < 32; ++s) r |= remvPart[s][tid];
      remv32[tid * 2]     = (unsigned int)r;
      remv32[tid * 2 + 1] = (unsigned int)(r >> 32);
    }
    __syncthreads();
    // ---- Phase B: sequential resolve of the tile's groups (LDS only) ----
    for (int gi = 0; gi < TW; ++gi) {
      const int g = G0 + gi;
      if (wave == 0) {
        ull cur = ((ull)remv32[gi * 2 + 1] << 32) | remv32[gi * 2];
        unsigned int clo = __builtin_amdgcn_readfirstlane((unsigned int)cur);
        unsigned int chi = __builtin_amdgcn_readfirstlane((unsigned int)(cur >> 32));
        cur = ((ull)chi << 32) | clo;
        ull mrow = tileRows[(gi * 64 + lane) * TRS + gi];
        const unsigned int ml = (unsigned int)mrow;
        const unsigned int mh = (unsigned int)(mrow >> 32);
        const ull validm = (g == WORDS - 1) ? 0xFFFFull : ~0ull;
        ull rem = (~cur) & validm;
        while (rem) {
          int b = __ffsll((long long)rem) - 1;
          b = __builtin_amdgcn_readfirstlane(b);
          ull m = ((ull)(unsigned int)__builtin_amdgcn_readlane((int)mh, b) << 32) |
                  (unsigned int)__builtin_amdgcn_readlane((int)ml, b);
          cur |= m;
          ull above = (b == 63) ? 0ull : (~0ull << (b + 1));
          rem = (~cur) & rem & above;
        }
        ull kb = (~cur) & validm;
        if (lane == 0) keepwords[g] = kb;
        int kc = kcLds;
        if ((kb >> lane) & 1ull) {
          int ofs = __popcll(lane ? (kb & ((1ull << lane) - 1ull)) : 0ull);
          klist[kc + ofs] = g * 64 + lane;
          newk[ofs] = gi * 64 + lane;   // local row index for FU
        }
        if (lane == 0) {
          int nk = __popcll(kb);
          nkLds = nk;
          kcLds = kc + nk;
          doneLds = (kc + nk >= TOPK2) ? 1 : 0;
        }
      }
      __syncthreads();
      if (doneLds) break;
      // forward-update remaining tile words with newly kept rows (LDS only)
      if (gi + 1 < TW) {
        int w = tid & 7, k0 = tid >> 3;
        int nk = nkLds;
        if (w > gi && w < TW) {
          ull acc = 0;
          for (int kk = k0; kk < nk; kk += 32) acc |= tileRows[newk[kk] * TRS + w];
          if (acc) {
            atomicOr(&remv32[w * 2], (unsigned int)acc);
            atomicOr(&remv32[w * 2 + 1], (unsigned int)(acc >> 32));
          }
        }
      }
      __syncthreads();
    }
    if (doneLds) break;
  }
}

// ---------------- compact kept boxes, sigmoid scores, write output ---------
__global__ __launch_bounds__(256) void finalize_kernel(const ull* __restrict__ keepwords,
                                                       const double* __restrict__ sBox,
                                                       const double* __restrict__ sLog,
                                                       float* __restrict__ out) {
  __shared__ int pref[WORDS];
  int t = threadIdx.x;
  if (t == 0) {
    int s = 0;
    for (int w = 0; w < WORDS; ++w) {
      pref[w] = s;
      s += __popcll(keepwords[w]);
    }
  }
  __syncthreads();
  if (t < WORDS) {
    ull kb = keepwords[t];
    int base = pref[t];
    while (kb) {
      int b = __ffsll((long long)kb) - 1;
      kb &= kb - 1;
      if (base < TOPK2) {
        int i = t * 64 + b;
        out[base * 4 + 0] = (float)sBox[(size_t)i * 4 + 0];
        out[base * 4 + 1] = (float)sBox[(size_t)i * 4 + 1];
        out[base * 4 + 2] = (float)sBox[(size_t)i * 4 + 2];
        out[base * 4 + 3] = (float)sBox[(size_t)i * 4 + 3];
        double L = sLog[i];
        out[TOPK2 * 4 + base] = (float)(1.0 / (1.0 + exp(-L)));
      }
      ++base;
    }
  }
}

// ---------------------------------------------------------------------------
extern "C" void kernel_launch(void* const* d_in, const int* in_sizes, int n_in,
                              void* d_out, int out_size, void* d_ws, size_t ws_size,
                              hipStream_t stream) {
  // inputs: 0 image(unused) 1 feat 2 rpn_w 3 rpn_b 4 cls_w 5 cls_b 6 box_w 7 box_b
  const float* feat  = (const float*)d_in[1];
  const float* rpn_w = (const float*)d_in[2];
  const float* rpn_b = (const float*)d_in[3];
  const float* cls_w = (const float*)d_in[4];
  const float* cls_b = (const float*)d_in[5];
  const float* box_w = (const float*)d_in[6];
  const float* box_b = (const float*)d_in[7];
  float* out = (float*)d_out;

  // workspace layout (bytes, all 16B aligned); total ~34.44 MB
  char* ws = (char*)d_ws;
  double* part     = (double*)(ws);                 // 2*512*2500*8 = 20,480,000
  double* logits   = (double*)(ws + 20480000);      // 22500*8     =    180,000
  double* boxesAll = (double*)(ws + 20660000);      // 22500*4*8   =    720,000
  int*    ranks    = (int*)   (ws + 21380000);      // 22500*4     =     90,000
  double* sBox     = (double*)(ws + 21470000);      // 10000*4*8   =    320,000
  double* sLog     = (double*)(ws + 21790000);      // 10000*8     =     80,000
  ull*    mask     = (ull*)   (ws + 21870000);      // 10000*157*8 = 12,560,000
  ull*    keepw    = (ull*)   (ws + 34430000);      // 157*8       =      1,256
  // mask region is multiply-overlaid (all stream-ordered, lifetimes disjoint):
  //   wT (4608*512*4 = 9,437,184 B): written by wtrans, read by conv_gemm,
  //      dead after conv_gemm completes.
  //   headsc (2500*48*8 = 960,000 B): written by heads_mm (after conv),
  //      read by decode_kernel, dead before iou_mask writes mask.
  float*  wT       = (float*) (ws + 21870000);
  double* headsc   = (double*)(ws + 21870000);

  hipMemsetAsync(d_out, 0, (TOPK2 * 4 + TOPK2) * sizeof(float), stream);
  hipMemsetAsync(ranks, 0, NBOX * sizeof(int), stream);
  hipMemsetAsync(keepw, 0, WORDS * sizeof(ull), stream);  // early-exit tail

  wtrans<<<dim3(128, 8), 256, 0, stream>>>(rpn_w, wT);
  conv_gemm<<<dim3(80, 8, 2), 256, 0, stream>>>(feat, wT, part);
  heads_mm<<<dim3(40, 6), 256, 0, stream>>>(part, rpn_b, cls_w, box_w, headsc);
  decode_kernel<<<88, 256, 0, stream>>>(headsc, cls_b, box_b, logits, boxesAll,
                                        out + TOPK2 * 5);
  rank_count<<<dim3(88, 11), 256, 0, stream>>>(logits, ranks);
  scatter_topk<<<88, 256, 0, stream>>>(logits, boxesAll, ranks, sLog, sBox);
  iou_mask<<<dim3(WORDS, 40), 256, 0, stream>>>(sBox, mask);
  nms_scan<<<1, 256, 0, stream>>>(mask, keepw);
  finalize_kernel<<<1, 256, 0, stream>>>(keepw, sBox, sLog, out);
}

// Round 12
// 766.530 us; speedup vs baseline: 1.1126x; 1.0079x over previous
//
#include <hip/hip_runtime.h>
#include <cstdint>
#include <cstddef>

// ---------------------------------------------------------------------------
// RPN pipeline, fp64-accurate (ordering-critical: top-k rank + NMS decisions).
// fp32 inputs; all reductions accumulate in double (fp32*fp32 exact in f64).
// R18 re-anchor 800.3us; R19 heads_mm LDS-shared -> 772.6us.
// R20: (a) rank_count split-loop (1 compare/iter, exactly equivalent);
//      (b) s_setprio(1) around conv MFMA burst (T5; 5 indep blocks/CU).
// ---------------------------------------------------------------------------

typedef unsigned long long ull;
typedef double d4 __attribute__((ext_vector_type(4)));

#define NANCH 9
#define NPIX  2500      // 50*50
#define CIN   512
#define COUT  512
#define KTOT  4608      // 512*9
#define KSEG  2304      // KTOT/2
#define NBOX  22500     // 2500*9
#define TOPK1 10000
#define TOPK2 2000
#define WORDS 157       // ceil(10000/64)
#define NHEAD 45        // 9 cls + 36 box channels
#define HPAD  48        // padded per-pixel stride for head scratch

// ---------------- one-shot weight transpose to tap-major k' ---------------
// wT[(tap*512+ci)*512 + co] = w[co*4608 + ci*9 + tap].  LDS-tiled so both
// global reads and writes are coalesced.  ~2.4M floats, few us.
__global__ __launch_bounds__(256) void wtrans(const float* __restrict__ w,
                                              float* __restrict__ wT) {
  __shared__ float t[36][65];
  const int ci0 = blockIdx.x * 4;    // 4 ci per block -> 36 (tap,ci) rows
  const int co0 = blockIdx.y * 64;
  const int tid = threadIdx.x;
  // read: thread (co_l, cq) reads 9 taps contiguously for one (co,ci)
  const int co_l = tid >> 2, cq = tid & 3;
  const float* src = w + (size_t)(co0 + co_l) * KTOT + (ci0 + cq) * 9;
#pragma unroll
  for (int r = 0; r < 9; ++r) t[r * 4 + cq][co_l] = src[r];
  __syncthreads();
  // write: thread (co_w, rw0) writes 9 rows, coalesced along co
  const int co_w = tid & 63, rw0 = tid >> 6;
#pragma unroll
  for (int m = 0; m < 9; ++m) {
    int rw = rw0 + 4 * m;            // 0..35
    int tap = rw >> 2, cqq = rw & 3;
    wT[((size_t)tap * 512 + ci0 + cqq) * 512 + co0 + co_w] = t[rw][co_w];
  }
}

// ---------------- conv 3x3 as implicit-im2col GEMM, f64 MFMA ---------------
// R14: wave-count x cheap-staging. Tap-major k' (A-tile = shifted masked
// coalesced copy of feat; B coalesced from wT) + 256-thread blocks, grid
// (80,8,2)=1280 = 5 blocks/CU -> 20 waves/CU. 267us, MfmaUtil ~61%
// (f64 MFMA floor is 154us). R20 adds setprio around the MFMA burst:
// 5 independently-phased blocks/CU = wave role diversity (T5 prereq).
__global__ __launch_bounds__(256, 5) void conv_gemm(const float* __restrict__ feat,
                                                    const float* __restrict__ wT,
                                                    double* __restrict__ part) {
  const int p0  = blockIdx.x * 32;
  const int co0 = blockIdx.y * 64;
  const int z   = blockIdx.z;
  const int kseg0 = z * KSEG;
  __shared__ float As[2][32][40];   // [buf][k][p]  f32, stride 40 (==8 mod 32)
  __shared__ float Bs[2][32][72];   // [buf][k][co] f32, stride 72 (==8 mod 32)
  const int tid  = threadIdx.x;      // 0..255
  const int lane = tid & 63;
  const int wave = tid >> 6;         // 0..3
  const int quad = lane >> 4;
  const int l16  = lane & 15;
  const int wp = (wave & 1) * 16;    // wave p offset in tile
  const int wc = (wave >> 1) * 32;   // wave co offset in tile
  // A loader: thread = (pixel plA, k-row kAr in 0..7); covers rows kAr+8*jj
  const int plA = tid & 31, kAr = tid >> 5;
  const int pB = p0 + plA;
  const int py = pB / 50, px = pB - py * 50;
  // B loader: thread = (co lane coB, k-row kBr in 0..3); covers rows kBr+4*s
  const int coB = tid & 63, kBr = tid >> 6;

  // ---- layout probe: learn the C/D register->(m,n) mapping ----
  int pmap[4];
  {
    double av_p = (quad == 0) ? (double)(l16 + 1) : (quad == 1 ? 1.0 : 0.0);
    double bv_p = (quad == 0) ? 1.0 : (quad == 1 ? (double)(1000 * (l16 + 1)) : 0.0);
    d4 dp = (d4){0.0, 0.0, 0.0, 0.0};
    dp = __builtin_amdgcn_mfma_f64_16x16x4f64(av_p, bv_p, dp, 0, 0, 0);
#pragma unroll
    for (int r = 0; r < 4; ++r) {
      int iv = (int)(dp[r] + 0.5);
      int mm = iv % 1000 - 1;   // p-id within the 16 block
      int nn = iv / 1000 - 1;   // co-id within the 16 block
      pmap[r] = (mm & 255) | (nn << 8);
    }
  }

  d4 acc[2];
#pragma unroll
  for (int i = 0; i < 2; ++i) acc[i] = (d4){0.0, 0.0, 0.0, 0.0};

  const int NCH = KSEG / 32;   // 72 chunks

  float fa[4], fb[8];

  // A loads for chunk cc: tap constant within chunk -> shifted masked copy
  auto loadA = [&](int cc) {
    int kk0 = kseg0 + cc * 32;
    int tap = kk0 >> 9;             // 0..8
    int ci0 = kk0 & 511;
    int ky = (tap * 11) >> 5;       // tap/3 for tap<9
    int kx = tap - 3 * ky;
    int yy = py + ky - 1, xx = px + kx - 1;
    bool valid = (pB < NPIX) && (yy >= 0) && (yy < 50) && (xx >= 0) && (xx < 50);
    int off = valid ? ((ci0 + kAr) * NPIX + yy * 50 + xx) : 0;
#pragma unroll
    for (int jj = 0; jj < 4; ++jj) {
      float v = feat[off + jj * 8 * NPIX];   // rows kAr+8*jj (in-bounds always)
      fa[jj] = valid ? v : 0.0f;
    }
  };
  // B loads for chunk cc: coalesced rows of wT
  auto loadB = [&](int cc) {
    const float* src = wT + (size_t)(kseg0 + cc * 32 + kBr) * 512 + co0 + coB;
#pragma unroll
    for (int s = 0; s < 8; ++s) fb[s] = src[s * 4 * 512];  // rows kBr+4*s
  };

  // ---- prologue: stage chunk 0 into buf 0; prefetch chunk 1 into regs ----
  loadA(0);
  loadB(0);
#pragma unroll
  for (int jj = 0; jj < 4; ++jj) As[0][kAr + 8 * jj][plA] = fa[jj];
#pragma unroll
  for (int s = 0; s < 8; ++s) Bs[0][kBr + 4 * s][coB] = fb[s];
  loadA(1);
  loadB(1);
  __syncthreads();

  for (int c = 0; c < NCH; ++c) {
    const int buf = c & 1;
    // stage chunk c+1 into the other buffer (regs loaded last iteration)
    if (c + 1 < NCH) {
#pragma unroll
      for (int jj = 0; jj < 4; ++jj) As[buf ^ 1][kAr + 8 * jj][plA] = fa[jj];
#pragma unroll
      for (int s = 0; s < 8; ++s) Bs[buf ^ 1][kBr + 4 * s][coB] = fb[s];
    }
    // issue global loads for chunk c+2 (retire during the MFMA burst)
    if (c + 2 < NCH) {
      loadA(c + 2);
      loadB(c + 2);
    }
    // MFMA burst from buf: 8 k-steps x 2 tile-MFMAs (1 A read feeds 2)
    __builtin_amdgcn_s_setprio(1);
#pragma unroll
    for (int kk = 0; kk < 32; kk += 4) {
      double av  = (double)As[buf][kk + quad][wp + l16];
      double bv0 = (double)Bs[buf][kk + quad][wc + l16];
      double bv1 = (double)Bs[buf][kk + quad][wc + 16 + l16];
      acc[0] = __builtin_amdgcn_mfma_f64_16x16x4f64(av, bv0, acc[0], 0, 0, 0);
      acc[1] = __builtin_amdgcn_mfma_f64_16x16x4f64(av, bv1, acc[1], 0, 0, 0);
    }
    __builtin_amdgcn_s_setprio(0);
    __syncthreads();  // iter-c writes of buf^1 <-> iter-c+1 reads of buf^1
  }
  // epilogue: probe-decoded scatter
  double* basez = part + (size_t)z * COUT * NPIX;
#pragma unroll
  for (int cj = 0; cj < 2; ++cj) {
#pragma unroll
    for (int r = 0; r < 4; ++r) {
      int mm = pmap[r] & 255, nn = pmap[r] >> 8;
      int p  = p0 + wp + mm;
      int co = co0 + wc + cj * 16 + nn;
      if (p < NPIX) basez[(size_t)co * NPIX + p] = acc[cj][r];
    }
  }
}

// ---------------- heads stage 1: LDS-shared 1x1-conv over part -------------
// R19: grid (40 px-tiles, 6 channel-octets) = 240 blocks, 4 waves: per 32-co
// chunk all 256 threads cooperatively stage v = relu(part0+part1+bias) into
// LDS (coalesced, double-buffered, reg-prefetch); each wave accumulates its
// 2 channels from LDS. Traffic 921 -> 123MB. Numerics BIT-IDENTICAL (co
// ascending, identical v expression). Measured part of 772.6us total.
__global__ __launch_bounds__(256) void heads_mm(
    const double* __restrict__ part, const float* __restrict__ rpn_b,
    const float* __restrict__ cls_w, const float* __restrict__ box_w,
    double* __restrict__ headsc) {
  __shared__ double vt[2][32][66];   // [buf][co][px], 33.8 KB total
  const int tid  = threadIdx.x;
  const int lane = tid & 63;
  const int wave = tid >> 6;
  const int p0 = blockIdx.x * 64;
  const int p  = p0 + lane;
  const bool act = p < NPIX;
  const int ob = __builtin_amdgcn_readfirstlane(blockIdx.y * 8 + wave * 2);
  const int o0 = ob, o1 = ob + 1;                 // o1 may be invalid (>=45)
  auto wptr = [&](int o) {
    int oc = o < NHEAD ? o : NHEAD - 1;           // clamp: junk acc, not written
    return (oc < 9) ? cls_w + (size_t)oc * CIN
                    : box_w + (size_t)(oc - 9) * CIN;
  };
  const float* w0p = wptr(o0);
  const float* w1p = wptr(o1);

  // staging role: thread (px = tid&63, cr = tid>>6) covers rows cr+4*s
  const int pl = tid & 63, cr = tid >> 6;
  const int pp = (p0 + pl < NPIX) ? (p0 + pl) : 0;   // clamp (junk, unread)
  const int NCHK = CIN / 32;                         // 16 chunks

  double ra[8], rb[8];
  auto loadC = [&](int cb) {                         // issue chunk's loads
#pragma unroll
    for (int s = 0; s < 8; ++s) {
      int row = cb + cr + 4 * s;
      ra[s] = part[(size_t)row * NPIX + pp];
      rb[s] = part[(size_t)(row + COUT) * NPIX + pp];
    }
  };
  auto storeC = [&](int buf, int cb) {               // regs -> LDS (v computed)
#pragma unroll
    for (int s = 0; s < 8; ++s) {
      int rloc = cr + 4 * s;
      double v = ra[s] + rb[s] + (double)rpn_b[cb + rloc];
      vt[buf][rloc][pl] = v > 0.0 ? v : 0.0;
    }
  };

  double acc0 = 0.0, acc1 = 0.0;

  // prologue: stage chunk 0 into buf 0; prefetch chunk 1 into regs
  loadC(0);
  storeC(0, 0);
  loadC(32);
  __syncthreads();

  for (int c = 0; c < NCHK; ++c) {
    const int buf = c & 1;
    const int cb = c * 32;
    if (c + 1 < NCHK) storeC(buf ^ 1, cb + 32);      // regs from last iter
    if (c + 2 < NCHK) loadC(cb + 64);                // retire during compute
#pragma unroll 8
    for (int col = 0; col < 32; ++col) {
      double v = vt[buf][col][lane];
      acc0 += (double)w0p[cb + col] * v;
      acc1 += (double)w1p[cb + col] * v;
    }
    __syncthreads();   // iter-c writes of buf^1 <-> iter-c+1 reads of buf^1
  }
  if (act) {
    if (o0 < NHEAD) headsc[(size_t)p * HPAD + o0] = acc0;
    if (o1 < NHEAD) headsc[(size_t)p * HPAD + o1] = acc1;
  }
}

// ---------------- heads stage 2: bias + anchor decode + clamp --------------
__global__ __launch_bounds__(256) void decode_kernel(
    const double* __restrict__ headsc, const float* __restrict__ cls_b,
    const float* __restrict__ box_b, double* __restrict__ logits,
    double* __restrict__ boxesAll, float* __restrict__ out_cls) {
  int idx = blockIdx.x * blockDim.x + threadIdx.x;
  if (idx >= NBOX) return;
  int p = idx / 9, a = idx - p * 9;
  int y = p / 50, x = p - y * 50;
  double sx = 16.0 * (double)x, sy = 16.0 * (double)y;
  const double scs[3] = {128.0, 256.0, 512.0};
  const double ars[3] = {0.5, 1.0, 2.0};
  double ar = ars[a / 3], sc = scs[a - (a / 3) * 3];
  double hr = sqrt(ar), wr = 1.0 / hr;
  double wv = wr * sc, hv = hr * sc;
  // jnp.round == round-half-even == rint under default rounding mode
  double bx0 = rint(-wv * 0.5), by0 = rint(-hv * 0.5);
  double bx1 = rint(wv * 0.5), by1 = rint(hv * 0.5);
  double a0 = sx + bx0, a1 = sy + by0, a2 = sx + bx1, a3 = sy + by1;
  double wA = a2 - a0, hA = a3 - a1;
  double cx = a0 + 0.5 * wA, cy = a1 + 0.5 * hA;
  const double* hp = headsc + (size_t)p * HPAD;
  double dx = hp[9 + a * 4 + 0] + (double)box_b[a * 4 + 0];
  double dy = hp[9 + a * 4 + 1] + (double)box_b[a * 4 + 1];
  double dw = hp[9 + a * 4 + 2] + (double)box_b[a * 4 + 2];
  double dh = hp[9 + a * 4 + 3] + (double)box_b[a * 4 + 3];
  double pcx = wA * dx + cx, pcy = hA * dy + cy;
  double pw = exp(dw) * wA, ph = exp(dh) * hA;
  double b0 = pcx - 0.5 * pw, b1 = pcy - 0.5 * ph;
  double b2 = pcx + 0.5 * pw, b3 = pcy + 0.5 * ph;
  b0 = fmin(fmax(b0, 0.0), 800.0);
  b1 = fmin(fmax(b1, 0.0), 800.0);
  b2 = fmin(fmax(b2, 0.0), 800.0);
  b3 = fmin(fmax(b3, 0.0), 800.0);
  boxesAll[(size_t)idx * 4 + 0] = b0;
  boxesAll[(size_t)idx * 4 + 1] = b1;
  boxesAll[(size_t)idx * 4 + 2] = b2;
  boxesAll[(size_t)idx * 4 + 3] = b3;
  double L = hp[a] + (double)cls_b[a];
  logits[idx] = L;
  out_cls[idx] = (float)L;
}

// ---------------- exact stable descending rank (== jax.lax.top_k order) ---
// R20: split-loop. Old inner loop evaluated (Lj>Li || (Lj==Li && j<i)) --
// 3 ops/iter. The tie-break boundary j<i is a CONSTANT within a chunk:
// tcut = clamp(i-j0, 0, jn). For t<tcut the predicate is exactly Lj >= Li;
// for t>=tcut exactly Lj > Li (self-compare false). One f64 compare per
// iteration, exactly equivalent (incl. +-0.0 and tie semantics).
__global__ __launch_bounds__(256) void rank_count(const double* __restrict__ logits,
                                                  int* __restrict__ ranks) {
  __shared__ double Ls[2048];
  int i = blockIdx.x * 256 + threadIdx.x;
  int j0 = blockIdx.y * 2048;
  int jn = NBOX - j0;
  if (jn > 2048) jn = 2048;
  for (int t = threadIdx.x; t < jn; t += 256) Ls[t] = logits[j0 + t];
  __syncthreads();
  if (i >= NBOX) return;
  double Li = logits[i];
  int tcut = i - j0;
  if (tcut < 0) tcut = 0;
  if (tcut > jn) tcut = jn;
  int cnt = 0;
#pragma unroll 8
  for (int t = 0; t < tcut; ++t) cnt += (Ls[t] >= Li) ? 1 : 0;
#pragma unroll 8
  for (int t = tcut; t < jn; ++t) cnt += (Ls[t] > Li) ? 1 : 0;
  atomicAdd(&ranks[i], cnt);
}

__global__ __launch_bounds__(256) void scatter_topk(const double* __restrict__ logits,
                                                    const double* __restrict__ boxesAll,
                                                    const int* __restrict__ ranks,
                                                    double* __restrict__ sLog,
                                                    double* __restrict__ sBox) {
  int i = blockIdx.x * 256 + threadIdx.x;
  if (i >= NBOX) return;
  int r = ranks[i];
  if (r < TOPK1) {
    sLog[r] = logits[i];
    sBox[(size_t)r * 4 + 0] = boxesAll[(size_t)i * 4 + 0];
    sBox[(size_t)r * 4 + 1] = boxesAll[(size_t)i * 4 + 1];
    sBox[(size_t)r * 4 + 2] = boxesAll[(size_t)i * 4 + 2];
    sBox[(size_t)r * 4 + 3] = boxesAll[(size_t)i * 4 + 3];
  }
}

// ---------------- pairwise IoU suppression bitmask (upper triangle) --------
__global__ __launch_bounds__(256) void iou_mask(const double* __restrict__ sb,
                                                ull* __restrict__ mask) {
  const int it = blockIdx.x;
  const int wt = blockIdx.y;
  if (wt * 4 + 3 < it) return;  // block only needed for words >= i/64
  __shared__ double ib[64][4];
  __shared__ double jb[256][4];
  const int tid = threadIdx.x;
  {
    int ii = it * 64 + (tid >> 2);
    int d = tid & 3;
    ib[tid >> 2][d] = (ii < TOPK1) ? sb[(size_t)ii * 4 + d] : 0.0;
  }
  for (int t = tid; t < 1024; t += 256) {
    int jj = wt * 256 + (t >> 2);
    jb[t >> 2][t & 3] = (jj < TOPK1) ? sb[(size_t)jj * 4 + (t & 3)] : 0.0;
  }
  __syncthreads();
  const int il = tid & 63, wl = tid >> 6;
  const int i = it * 64 + il;
  const int word = wt * 4 + wl;
  if (i >= TOPK1 || word >= WORDS || word < (i >> 6)) return;
  const double x0 = ib[il][0], y0 = ib[il][1], x1 = ib[il][2], y1 = ib[il][3];
  const double areai = (x1 - x0) * (y1 - y0);
  ull bits = 0;
  const int jbase = word * 64;
  for (int b = 0; b < 64; ++b) {
    int j = jbase + b;
    if (j <= i || j >= TOPK1) continue;
    int jl = wl * 64 + b;
    double u0 = jb[jl][0], u1 = jb[jl][1], u2 = jb[jl][2], u3 = jb[jl][3];
    double xl = fmax(x0, u0), yt = fmax(y0, u1);
    double xr = fmin(x1, u2), yb = fmin(y1, u3);
    double iw = xr - xl, ih = yb - yt;
    iw = iw > 0.0 ? iw : 0.0;
    ih = ih > 0.0 ? ih : 0.0;
    double inter = iw * ih;
    double aj = (u2 - u0) * (u3 - u1);
    double un = areai + aj - inter;
    // reference: inter/un > 0.7 (0/0 -> NaN -> false). Multiply form matches.
    if (inter > 0.7 * un) bits |= 1ull << b;
  }
  mask[(size_t)i * WORDS + word] = bits;
}

// ---------------- tiled greedy-NMS scan, LDS-resident tile -----------------
#define NTILE 8
#define TRS   10    // padded ull stride for tileRows (8 words + 2 pad)
#define KCAP  2112

__global__ __launch_bounds__(256) void nms_scan(const ull* __restrict__ mask,
                                                ull* __restrict__ keepwords) {
  __shared__ ull tileRows[512 * TRS];        // 40,960 B
  __shared__ int klist[KCAP];                // kept global indices (rank order)
  __shared__ ull remvPart[32][NTILE + 1];    // column-OR partials
  __shared__ unsigned int remv32[NTILE * 2]; // removal words (lo/hi pairs)
  __shared__ int newk[64];                   // this group's kept local rows
  __shared__ int kcLds, nkLds, doneLds;
  const int tid = threadIdx.x;
  const int lane = tid & 63;
  const int wave = tid >> 6;
  if (tid == 0) { kcLds = 0; nkLds = 0; doneLds = 0; }
  __syncthreads();

  for (int T = 0; T < (WORDS + NTILE - 1) / NTILE; ++T) {
    const int G0 = T * NTILE;
    const int TW = (WORDS - G0 < NTILE) ? (WORDS - G0) : NTILE;
    const int kc0 = kcLds;
    // ---- Phase A1: stage tile rows (512 x TW words) into LDS ----
#pragma unroll
    for (int pass = 0; pass < 8; ++pass) {
      int lr = pass * 64 + (tid >> 2);   // local row 0..511
      int w  = (tid & 3) * 2;            // word pair
      int gr = G0 * 64 + lr;             // global row
      ull v0 = 0, v1 = 0;
      if (gr < TOPK1) {
        const ull* row = mask + (size_t)gr * WORDS + G0;
        if (w < TW)     v0 = row[w];
        if (w + 1 < TW) v1 = row[w + 1];
      }
      tileRows[lr * TRS + w]     = v0;
      tileRows[lr * TRS + w + 1] = v1;
    }
    // ---- Phase A2: base removal words = OR over previously-kept rows ----
    {
      int w = tid & 7, stripe = tid >> 3;   // 32 stripes x 8 words
      ull acc = 0;
      if (w < TW) {
        int t = stripe;
        for (; t + 224 < kc0; t += 256) {
          ull a0 = mask[(size_t)klist[t      ] * WORDS + G0 + w];
          ull a1 = mask[(size_t)klist[t +  32] * WORDS + G0 + w];
          ull a2 = mask[(size_t)klist[t +  64] * WORDS + G0 + w];
          ull a3 = mask[(size_t)klist[t +  96] * WORDS + G0 + w];
          ull a4 = mask[(size_t)klist[t + 128] * WORDS + G0 + w];
          ull a5 = mask[(size_t)klist[t + 160] * WORDS + G0 + w];
          ull a6 = mask[(size_t)klist[t + 192] * WORDS + G0 + w];
          ull a7 = mask[(size_t)klist[t + 224] * WORDS + G0 + w];
          acc |= ((a0 | a1) | (a2 | a3)) | ((a4 | a5) | (a6 | a7));
        }
        for (; t < kc0; t += 32) acc |= mask[(size_t)klist[t] * WORDS + G0 + w];
      }
      remvPart[stripe][w] = acc;
    }
    __syncthreads();
    if (tid < NTILE) {
      ull r = 0;
#pragma unroll
      for (int s = 0; s < 32; ++s) r |= remvPart[s][tid];
      remv32[tid * 2]     = (unsigned int)r;
      remv32[tid * 2 + 1] = (unsigned int)(r >> 32);
    }
    __syncthreads();
    // ---- Phase B: sequential resolve of the tile's groups (LDS only) ----
    for (int gi = 0; gi < TW; ++gi) {
      const int g = G0 + gi;
      if (wave == 0) {
        ull cur = ((ull)remv32[gi * 2 + 1] << 32) | remv32[gi * 2];
        unsigned int clo = __builtin_amdgcn_readfirstlane((unsigned int)cur);
        unsigned int chi = __builtin_amdgcn_readfirstlane((unsigned int)(cur >> 32));
        cur = ((ull)chi << 32) | clo;
        ull mrow = tileRows[(gi * 64 + lane) * TRS + gi];
        const unsigned int ml = (unsigned int)mrow;
        const unsigned int mh = (unsigned int)(mrow >> 32);
        const ull validm = (g == WORDS - 1) ? 0xFFFFull : ~0ull;
        ull rem = (~cur) & validm;
        while (rem) {
          int b = __ffsll((long long)rem) - 1;
          b = __builtin_amdgcn_readfirstlane(b);
          ull m = ((ull)(unsigned int)__builtin_amdgcn_readlane((int)mh, b) << 32) |
                  (unsigned int)__builtin_amdgcn_readlane((int)ml, b);
          cur |= m;
          ull above = (b == 63) ? 0ull : (~0ull << (b + 1));
          rem = (~cur) & rem & above;
        }
        ull kb = (~cur) & validm;
        if (lane == 0) keepwords[g] = kb;
        int kc = kcLds;
        if ((kb >> lane) & 1ull) {
          int ofs = __popcll(lane ? (kb & ((1ull << lane) - 1ull)) : 0ull);
          klist[kc + ofs] = g * 64 + lane;
          newk[ofs] = gi * 64 + lane;   // local row index for FU
        }
        if (lane == 0) {
          int nk = __popcll(kb);
          nkLds = nk;
          kcLds = kc + nk;
          doneLds = (kc + nk >= TOPK2) ? 1 : 0;
        }
      }
      __syncthreads();
      if (doneLds) break;
      // forward-update remaining tile words with newly kept rows (LDS only)
      if (gi + 1 < TW) {
        int w = tid & 7, k0 = tid >> 3;
        int nk = nkLds;
        if (w > gi && w < TW) {
          ull acc = 0;
          for (int kk = k0; kk < nk; kk += 32) acc |= tileRows[newk[kk] * TRS + w];
          if (acc) {
            atomicOr(&remv32[w * 2], (unsigned int)acc);
            atomicOr(&remv32[w * 2 + 1], (unsigned int)(acc >> 32));
          }
        }
      }
      __syncthreads();
    }
    if (doneLds) break;
  }
}

// ---------------- compact kept boxes, sigmoid scores, write output ---------
__global__ __launch_bounds__(256) void finalize_kernel(const ull* __restrict__ keepwords,
                                                       const double* __restrict__ sBox,
                                                       const double* __restrict__ sLog,
                                                       float* __restrict__ out) {
  __shared__ int pref[WORDS];
  int t = threadIdx.x;
  if (t == 0) {
    int s = 0;
    for (int w = 0; w < WORDS; ++w) {
      pref[w] = s;
      s += __popcll(keepwords[w]);
    }
  }
  __syncthreads();
  if (t < WORDS) {
    ull kb = keepwords[t];
    int base = pref[t];
    while (kb) {
      int b = __ffsll((long long)kb) - 1;
      kb &= kb - 1;
      if (base < TOPK2) {
        int i = t * 64 + b;
        out[base * 4 + 0] = (float)sBox[(size_t)i * 4 + 0];
        out[base * 4 + 1] = (float)sBox[(size_t)i * 4 + 1];
        out[base * 4 + 2] = (float)sBox[(size_t)i * 4 + 2];
        out[base * 4 + 3] = (float)sBox[(size_t)i * 4 + 3];
        double L = sLog[i];
        out[TOPK2 * 4 + base] = (float)(1.0 / (1.0 + exp(-L)));
      }
      ++base;
    }
  }
}

// ---------------------------------------------------------------------------
extern "C" void kernel_launch(void* const* d_in, const int* in_sizes, int n_in,
                              void* d_out, int out_size, void* d_ws, size_t ws_size,
                              hipStream_t stream) {
  // inputs: 0 image(unused) 1 feat 2 rpn_w 3 rpn_b 4 cls_w 5 cls_b 6 box_w 7 box_b
  const float* feat  = (const float*)d_in[1];
  const float* rpn_w = (const float*)d_in[2];
  const float* rpn_b = (const float*)d_in[3];
  const float* cls_w = (const float*)d_in[4];
  const float* cls_b = (const float*)d_in[5];
  const float* box_w = (const float*)d_in[6];
  const float* box_b = (const float*)d_in[7];
  float* out = (float*)d_out;

  // workspace layout (bytes, all 16B aligned); total ~34.44 MB
  char* ws = (char*)d_ws;
  double* part     = (double*)(ws);                 // 2*512*2500*8 = 20,480,000
  double* logits   = (double*)(ws + 20480000);      // 22500*8     =    180,000
  double* boxesAll = (double*)(ws + 20660000);      // 22500*4*8   =    720,000
  int*    ranks    = (int*)   (ws + 21380000);      // 22500*4     =     90,000
  double* sBox     = (double*)(ws + 21470000);      // 10000*4*8   =    320,000
  double* sLog     = (double*)(ws + 21790000);      // 10000*8     =     80,000
  ull*    mask     = (ull*)   (ws + 21870000);      // 10000*157*8 = 12,560,000
  ull*    keepw    = (ull*)   (ws + 34430000);      // 157*8       =      1,256
  // mask region is multiply-overlaid (all stream-ordered, lifetimes disjoint):
  //   wT (4608*512*4 = 9,437,184 B): written by wtrans, read by conv_gemm,
  //      dead after conv_gemm completes.
  //   headsc (2500*48*8 = 960,000 B): written by heads_mm (after conv),
  //      read by decode_kernel, dead before iou_mask writes mask.
  float*  wT       = (float*) (ws + 21870000);
  double* headsc   = (double*)(ws + 21870000);

  hipMemsetAsync(d_out, 0, (TOPK2 * 4 + TOPK2) * sizeof(float), stream);
  hipMemsetAsync(ranks, 0, NBOX * sizeof(int), stream);
  hipMemsetAsync(keepw, 0, WORDS * sizeof(ull), stream);  // early-exit tail

  wtrans<<<dim3(128, 8), 256, 0, stream>>>(rpn_w, wT);
  conv_gemm<<<dim3(80, 8, 2), 256, 0, stream>>>(feat, wT, part);
  heads_mm<<<dim3(40, 6), 256, 0, stream>>>(part, rpn_b, cls_w, box_w, headsc);
  decode_kernel<<<88, 256, 0, stream>>>(headsc, cls_b, box_b, logits, boxesAll,
                                        out + TOPK2 * 5);
  rank_count<<<dim3(88, 11), 256, 0, stream>>>(logits, ranks);
  scatter_topk<<<88, 256, 0, stream>>>(logits, boxesAll, ranks, sLog, sBox);
  iou_mask<<<dim3(WORDS, 40), 256, 0, stream>>>(sBox, mask);
  nms_scan<<<1, 256, 0, stream>>>(mask, keepw);
  finalize_kernel<<<1, 256, 0, stream>>>(keepw, sBox, sLog, out);
}